// Round 1
// baseline (435.826 us; speedup 1.0000x reference)
//
#include <hip/hip_runtime.h>
#include <hip/hip_bf16.h>

#define D 96
#define ASTR 104       // LDS bf16 row stride (halves): 208B, 16B-aligned, 2-way banks (free)
#define WSTR 104

typedef __attribute__((ext_vector_type(8))) short short8;   // 8 bf16 = 4 VGPRs
typedef __attribute__((ext_vector_type(4))) float f32x4v;   // MFMA accumulator

__device__ inline float blo(unsigned u) { return __uint_as_float(u << 16); }
__device__ inline float bhi(unsigned u) { return __uint_as_float(u & 0xffff0000u); }

// ---------------- copy x into out[:, 0:96] and bf16 mirror ----------------
__global__ void k_copyx(const float* __restrict__ x, float* __restrict__ out,
                        __hip_bfloat16* __restrict__ h16, int n) {
    int idx = blockIdx.x * blockDim.x + threadIdx.x;   // n*24 float4s
    if (idx >= n * 24) return;
    int r = idx / 24, c = idx - r * 24;
    float4 v = ((const float4*)x)[r * 24 + c];
    ((float4*)out)[r * 96 + c] = v;
    union { __hip_bfloat16 hh[4]; uint2 u; } p;
    p.hh[0] = __float2bfloat16(v.x); p.hh[1] = __float2bfloat16(v.y);
    p.hh[2] = __float2bfloat16(v.z); p.hh[3] = __float2bfloat16(v.w);
    ((uint2*)h16)[r * 24 + c] = p.u;
}

// ---------------- weight prep: fp32 [k][n] -> bf16 transposed [n][k] stride 104 ----------------
__global__ void k_prep(const float* __restrict__ w10, const float* __restrict__ w20,
                       const float* __restrict__ w11, const float* __restrict__ w21,
                       const float* __restrict__ w12, const float* __restrict__ w22,
                       __hip_bfloat16* __restrict__ wTg) {
    int idx = blockIdx.x * blockDim.x + threadIdx.x;   // 6*9216
    if (idx >= 6 * 9216) return;
    int m = idx / 9216, i = idx - m * 9216;
    int k = i / 96, nn = i - k * 96;
    const float* W;
    switch (m) {
        case 0: W = w10; break; case 1: W = w20; break;
        case 2: W = w11; break; case 3: W = w21; break;
        case 4: W = w12; break; default: W = w22; break;
    }
    wTg[(size_t)m * (96 * WSTR) + nn * WSTR + k] = __float2bfloat16(W[k * 96 + nn]);
}

// ---------------- direct 1-level CSR build ----------------
// per-node in-degree histogram (fire-and-forget atomics into 200KB, L2-resident)
__global__ __launch_bounds__(256) void k_count(const int* __restrict__ dst,
                                               int* __restrict__ cnt, int E) {
    int stride = gridDim.x * 256;
    for (int e = blockIdx.x * 256 + threadIdx.x; e < E; e += stride)
        atomicAdd(&cnt[dst[e]], 1);
}

// exclusive scan of cnt[n] -> rowstart[n+1] + cursor[n]; single block, 1024 threads
__global__ __launch_bounds__(1024) void k_scan(const int* __restrict__ cnt,
                                               int* __restrict__ rowstart,
                                               int* __restrict__ cursor, int n) {
    __shared__ int ws[1024];
    int t = threadIdx.x;
    int per = (n + 1023) >> 10;                 // 49 for n=50000
    int i0 = t * per;
    int i1 = min(i0 + per, n);
    int s = 0;
    for (int i = i0; i < i1; i++) s += cnt[i];
    ws[t] = s;
    __syncthreads();
    for (int off = 1; off < 1024; off <<= 1) {
        int u = (t >= off) ? ws[t - off] : 0;
        __syncthreads();
        ws[t] += u;
        __syncthreads();
    }
    int base = ws[t] - s;                       // exclusive prefix
    for (int i = i0; i < i1; i++) {
        int c = cnt[i];
        rowstart[i] = base; cursor[i] = base;
        base += c;
    }
    if (t == 1023) rowstart[n] = ws[1023];      // == E
}

// direct scatter: pos = atomicAdd(cursor[dst]); ecsr[pos] = src
__global__ __launch_bounds__(256) void k_scatter(const int* __restrict__ src,
                                                 const int* __restrict__ dst,
                                                 int* __restrict__ cursor,
                                                 int* __restrict__ ecsr, int E) {
    int stride = gridDim.x * 256;
    for (int e = blockIdx.x * 256 + threadIdx.x; e < E; e += stride) {
        int d = dst[e];
        int p = atomicAdd(&cursor[d], 1);
        ecsr[p] = src[e];
    }
}

// ---------------- GIN aggregation (bf16 rows): t[i] = h[i] + sum h[s] ----------------
// 32-lane group per node; lanes 0-23 each hold one dwordx2 (4 bf16) of the 192B row.
__global__ __launch_bounds__(256) void k_aggr(const __hip_bfloat16* __restrict__ h16,
                                              const int* __restrict__ rowstart,
                                              const int* __restrict__ ecsr,
                                              __hip_bfloat16* __restrict__ t16, int n) {
    int g = (blockIdx.x * 256 + threadIdx.x) >> 5;      // node id
    int lane = threadIdx.x & 31;
    if (g >= n || lane >= 24) return;
    const uint2* hp = (const uint2*)h16;                // 24 uint2 per row
    uint2 u = hp[(size_t)g * 24 + lane];                // self term (eps=0)
    float ax = blo(u.x), ay = bhi(u.x), az = blo(u.y), aw = bhi(u.y);
    int e0 = rowstart[g], e1 = rowstart[g + 1];
    int k = e0;
    for (; k + 4 <= e1; k += 4) {                       // 4 gathers in flight
        int s0 = ecsr[k], s1 = ecsr[k + 1], s2 = ecsr[k + 2], s3 = ecsr[k + 3];
        uint2 v0 = hp[(size_t)s0 * 24 + lane];
        uint2 v1 = hp[(size_t)s1 * 24 + lane];
        uint2 v2 = hp[(size_t)s2 * 24 + lane];
        uint2 v3 = hp[(size_t)s3 * 24 + lane];
        ax += blo(v0.x) + blo(v1.x) + blo(v2.x) + blo(v3.x);
        ay += bhi(v0.x) + bhi(v1.x) + bhi(v2.x) + bhi(v3.x);
        az += blo(v0.y) + blo(v1.y) + blo(v2.y) + blo(v3.y);
        aw += bhi(v0.y) + bhi(v1.y) + bhi(v2.y) + bhi(v3.y);
    }
    for (; k < e1; k++) {
        int s = ecsr[k];
        uint2 v = hp[(size_t)s * 24 + lane];
        ax += blo(v.x); ay += bhi(v.x); az += blo(v.y); aw += bhi(v.y);
    }
    union { __hip_bfloat16 hh[4]; uint2 uu; } p;
    p.hh[0] = __float2bfloat16(ax); p.hh[1] = __float2bfloat16(ay);
    p.hh[2] = __float2bfloat16(az); p.hh[3] = __float2bfloat16(aw);
    ((uint2*)t16)[(size_t)g * 24 + lane] = p.uu;
}

// ---------------- MFMA MLP: h = relu(t@W1+b1)@W2 + b2 ----------------
// 64 rows/block, 4 waves; wave w owns 16-row band. 6 n-tiles x 3 k-steps per pass.
__global__ __launch_bounds__(256) void k_mlpm(const __hip_bfloat16* __restrict__ t16,
                                              const __hip_bfloat16* __restrict__ w1t,
                                              const float* __restrict__ B1,
                                              const __hip_bfloat16* __restrict__ w2t,
                                              const float* __restrict__ B2,
                                              __hip_bfloat16* __restrict__ h16,
                                              float* __restrict__ out,
                                              int n, int ocol) {
    __shared__ __align__(16) short aT[64 * ASTR];   // activations / y1, bf16
    __shared__ __align__(16) short wS[96 * WSTR];   // current weight, bf16 transposed

    const int tid = threadIdx.x;
    const int row0 = blockIdx.x * 64;
    const int lane = tid & 63;
    const int wv = __builtin_amdgcn_readfirstlane(tid >> 6);
    const int wr0 = wv * 16;                         // wave's row band
    const int quad = lane >> 4;
    const int r = lane & 15;

    // stage 64 rows of t16 (8B chunks) and W1
    {
        const uint2* tsrc = (const uint2*)t16;
        for (int idx = tid; idx < 64 * 24; idx += 256) {
            int rr = idx / 24, c = idx - rr * 24;
            int gr = row0 + rr; if (gr >= n) gr = n - 1;
            *(uint2*)&aT[rr * ASTR + c * 4] = tsrc[(size_t)gr * 24 + c];
        }
        const unsigned* wsrc = (const unsigned*)w1t;
        unsigned* wdst = (unsigned*)wS;
        for (int idx = tid; idx < 96 * WSTR / 2; idx += 256) wdst[idx] = wsrc[idx];
    }
    __syncthreads();

    // A fragments: A[m=r][k=quad*8+j]
    short8 af[3];
    #pragma unroll
    for (int ksi = 0; ksi < 3; ksi++)
        af[ksi] = *(const short8*)&aT[(wr0 + r) * ASTR + ksi * 32 + quad * 8];

    // ---- pass 1 ----
    f32x4v c1[6];
    #pragma unroll
    for (int nt = 0; nt < 6; nt++) {
        f32x4v c = {0.f, 0.f, 0.f, 0.f};
        #pragma unroll
        for (int ksi = 0; ksi < 3; ksi++) {
            short8 bfr = *(const short8*)&wS[(nt * 16 + r) * WSTR + ksi * 32 + quad * 8];
            c = __builtin_amdgcn_mfma_f32_16x16x32_bf16(af[ksi], bfr, c, 0, 0, 0);
        }
        c1[nt] = c;
    }
    __syncthreads();                                 // everyone done reading W1

    // y1 = relu(c + b1) -> bf16 into own band of aT; restage W2
    #pragma unroll
    for (int nt = 0; nt < 6; nt++) {
        float bv = B1[nt * 16 + r];
        #pragma unroll
        for (int i = 0; i < 4; i++) {
            float y = fmaxf(c1[nt][i] + bv, 0.f);
            __hip_bfloat16 hb = __float2bfloat16(y);
            aT[(wr0 + quad * 4 + i) * ASTR + nt * 16 + r] = *(short*)&hb;
        }
    }
    {
        const unsigned* wsrc = (const unsigned*)w2t;
        unsigned* wdst = (unsigned*)wS;
        for (int idx = tid; idx < 96 * WSTR / 2; idx += 256) wdst[idx] = wsrc[idx];
    }
    __syncthreads();

    // ---- pass 2 ----
    short8 af2[3];
    #pragma unroll
    for (int ksi = 0; ksi < 3; ksi++)
        af2[ksi] = *(const short8*)&aT[(wr0 + r) * ASTR + ksi * 32 + quad * 8];

    #pragma unroll
    for (int nt = 0; nt < 6; nt++) {
        f32x4v c = {0.f, 0.f, 0.f, 0.f};
        #pragma unroll
        for (int ksi = 0; ksi < 3; ksi++) {
            short8 bfr = *(const short8*)&wS[(nt * 16 + r) * WSTR + ksi * 32 + quad * 8];
            c = __builtin_amdgcn_mfma_f32_16x16x32_bf16(af2[ksi], bfr, c, 0, 0, 0);
        }
        float bv = B2[nt * 16 + r];
        int col = nt * 16 + r;
        #pragma unroll
        for (int i = 0; i < 4; i++) {
            int gr = row0 + wr0 + quad * 4 + i;
            if (gr < n) {
                float v = c[i] + bv;
                out[(size_t)gr * 384 + ocol + col] = v;
                h16[(size_t)gr * D + col] = __float2bfloat16(v);
            }
        }
    }
}

extern "C" void kernel_launch(void* const* d_in, const int* in_sizes, int n_in,
                              void* d_out, int out_size, void* d_ws, size_t ws_size,
                              hipStream_t stream) {
    const float* x = (const float*)d_in[0];
    const int* ei = (const int*)d_in[1];
    const int n = in_sizes[0] / D;           // 50000
    const int E = in_sizes[1] / 2;           // 800000
    const int* src = ei;
    const int* dst = ei + E;
    float* out = (float*)d_out;

    // workspace layout (byte offsets, all 16B-aligned)
    char* ws = (char*)d_ws;
    __hip_bfloat16* t16  = (__hip_bfloat16*)ws;                  // n*96 halves = 9.6 MB
    __hip_bfloat16* h16  = (__hip_bfloat16*)(ws + 9600000);      // n*96 halves = 9.6 MB
    __hip_bfloat16* wTg  = (__hip_bfloat16*)(ws + 19200000);     // 6*96*104 halves ~ 120 KB
    int*   rowcnt   = (int*)(ws + 19400000);                     // n ints = 200 KB
    int*   rowstart = (int*)(ws + 19600000);                     // n+1 ints
    int*   cursor   = (int*)(ws + 19800016);                     // n ints
    int*   ecsr     = (int*)(ws + 20000064);                     // E ints = 3.2 MB

    // out[:,0:96] = x ; h16 = bf16(x)
    k_copyx<<<(n * 24 + 255) / 256, 256, 0, stream>>>(x, out, h16, n);

    // weights -> bf16 transposed
    k_prep<<<(6 * 9216 + 255) / 256, 256, 0, stream>>>(
        (const float*)d_in[2], (const float*)d_in[4],
        (const float*)d_in[6], (const float*)d_in[8],
        (const float*)d_in[10], (const float*)d_in[12], wTg);

    // direct 1-level CSR build (once; shared by all 3 layers)
    hipMemsetAsync(rowcnt, 0, (size_t)n * sizeof(int), stream);
    k_count<<<2048, 256, 0, stream>>>(dst, rowcnt, E);
    k_scan<<<1, 1024, 0, stream>>>(rowcnt, rowstart, cursor, n);
    k_scatter<<<2048, 256, 0, stream>>>(src, dst, cursor, ecsr, E);

    const int aggr_grid = (n * 32 + 255) / 256;
    const int mlp_grid  = (n + 63) / 64;

    for (int l = 0; l < 3; l++) {
        const float* B1 = (const float*)d_in[3 + 4 * l];
        const float* B2 = (const float*)d_in[5 + 4 * l];
        const __hip_bfloat16* w1t = wTg + (size_t)(2 * l) * (96 * WSTR);
        const __hip_bfloat16* w2t = wTg + (size_t)(2 * l + 1) * (96 * WSTR);
        k_aggr<<<aggr_grid, 256, 0, stream>>>(h16, rowstart, ecsr, t16, n);
        k_mlpm<<<mlp_grid, 256, 0, stream>>>(t16, w1t, B1, w2t, B2, h16, out, n, (l + 1) * D);
    }
}

// Round 2
// 323.546 us; speedup vs baseline: 1.3470x; 1.3470x over previous
//
#include <hip/hip_runtime.h>
#include <hip/hip_bf16.h>

#define D 96
#define ASTR 104       // LDS bf16 row stride (halves): 208B, 16B-aligned, 2-way banks (free)
#define WSTR 104

typedef __attribute__((ext_vector_type(8))) short short8;   // 8 bf16 = 4 VGPRs
typedef __attribute__((ext_vector_type(4))) float f32x4v;   // MFMA accumulator

struct u3 { unsigned x, y, z; };                            // 12B row chunk (dwordx3)

__device__ inline float blo(unsigned u) { return __uint_as_float(u << 16); }
__device__ inline float bhi(unsigned u) { return __uint_as_float(u & 0xffff0000u); }

// ---------------- copy x into out[:, 0:96] and bf16 mirror ----------------
__global__ void k_copyx(const float* __restrict__ x, float* __restrict__ out,
                        __hip_bfloat16* __restrict__ h16, int n) {
    int idx = blockIdx.x * blockDim.x + threadIdx.x;   // n*24 float4s
    if (idx >= n * 24) return;
    int r = idx / 24, c = idx - r * 24;
    float4 v = ((const float4*)x)[r * 24 + c];
    ((float4*)out)[r * 96 + c] = v;
    union { __hip_bfloat16 hh[4]; uint2 u; } p;
    p.hh[0] = __float2bfloat16(v.x); p.hh[1] = __float2bfloat16(v.y);
    p.hh[2] = __float2bfloat16(v.z); p.hh[3] = __float2bfloat16(v.w);
    ((uint2*)h16)[r * 24 + c] = p.u;
}

// ---------------- weight prep: fp32 [k][n] -> bf16 transposed [n][k] stride 104 ----------------
__global__ void k_prep(const float* __restrict__ w10, const float* __restrict__ w20,
                       const float* __restrict__ w11, const float* __restrict__ w21,
                       const float* __restrict__ w12, const float* __restrict__ w22,
                       __hip_bfloat16* __restrict__ wTg) {
    int idx = blockIdx.x * blockDim.x + threadIdx.x;   // 6*9216
    if (idx >= 6 * 9216) return;
    int m = idx / 9216, i = idx - m * 9216;
    int k = i / 96, nn = i - k * 96;
    const float* W;
    switch (m) {
        case 0: W = w10; break; case 1: W = w20; break;
        case 2: W = w11; break; case 3: W = w21; break;
        case 4: W = w12; break; default: W = w22; break;
    }
    wTg[(size_t)m * (96 * WSTR) + nn * WSTR + k] = __float2bfloat16(W[k * 96 + nn]);
}

// ---------------- direct 1-level CSR build ----------------
// per-node in-degree histogram (fire-and-forget atomics, L2-resident counters)
__global__ __launch_bounds__(256) void k_count(const int* __restrict__ dst,
                                               int* __restrict__ cnt, int E) {
    int stride = gridDim.x * 256;
    for (int e = blockIdx.x * 256 + threadIdx.x; e < E; e += stride)
        atomicAdd(&cnt[dst[e]], 1);
}

// hierarchical scan, stage 1: per-block inclusive scan -> exclusive partials + block sums
__global__ __launch_bounds__(256) void k_scan_up(const int* __restrict__ cnt,
                                                 int* __restrict__ excl,
                                                 int* __restrict__ bsum, int n) {
    __shared__ int s[256];
    int t = threadIdx.x, b = blockIdx.x;
    int i = b * 256 + t;
    int v = (i < n) ? cnt[i] : 0;
    s[t] = v;
    __syncthreads();
    for (int off = 1; off < 256; off <<= 1) {
        int u = (t >= off) ? s[t - off] : 0;
        __syncthreads();
        s[t] += u;
        __syncthreads();
    }
    if (i < n) excl[i] = s[t] - v;          // exclusive within block
    if (t == 255) bsum[b] = s[255];         // block total
}

// stage 2: single-block exclusive scan of block sums (nb <= 256)
__global__ __launch_bounds__(256) void k_scan_mid(const int* __restrict__ bsum,
                                                  int* __restrict__ boff, int nb) {
    __shared__ int s[256];
    int t = threadIdx.x;
    int v = (t < nb) ? bsum[t] : 0;
    s[t] = v;
    __syncthreads();
    for (int off = 1; off < 256; off <<= 1) {
        int u = (t >= off) ? s[t - off] : 0;
        __syncthreads();
        s[t] += u;
        __syncthreads();
    }
    if (t < nb) boff[t] = s[t] - v;         // exclusive
}

// stage 3: add block offset in place, duplicate into cursor, set rowstart[n]=E
__global__ __launch_bounds__(256) void k_scan_down(int* __restrict__ rowstart,
                                                   const int* __restrict__ boff,
                                                   int* __restrict__ cursor,
                                                   int n, int E) {
    int b = blockIdx.x, t = threadIdx.x;
    int i = b * 256 + t;
    if (i < n) {
        int v = rowstart[i] + boff[b];
        rowstart[i] = v;
        cursor[i] = v;
    }
    if (i == 0) rowstart[n] = E;
}

// direct scatter: pos = atomicAdd(cursor[dst]); ecsr[pos] = src
__global__ __launch_bounds__(256) void k_scatter(const int* __restrict__ src,
                                                 const int* __restrict__ dst,
                                                 int* __restrict__ cursor,
                                                 int* __restrict__ ecsr, int E) {
    int stride = gridDim.x * 256;
    for (int e = blockIdx.x * 256 + threadIdx.x; e < E; e += stride) {
        int d = dst[e];
        int p = atomicAdd(&cursor[d], 1);
        ecsr[p] = src[e];
    }
}

// ---------------- GIN aggregation (bf16 rows): t[i] = h[i] + sum h[s] ----------------
// 16-lane group per node; lane l holds dwords [3l,3l+3) of the 192B row (dwordx3).
// 100% lane utilization, 4 nodes per wave.
__global__ __launch_bounds__(256) void k_aggr(const __hip_bfloat16* __restrict__ h16,
                                              const int* __restrict__ rowstart,
                                              const int* __restrict__ ecsr,
                                              __hip_bfloat16* __restrict__ t16, int n) {
    int g = (blockIdx.x * 256 + threadIdx.x) >> 4;      // node id
    int lane = threadIdx.x & 15;
    if (g >= n) return;
    const u3* hp = (const u3*)h16;                      // 16 u3 per row
    u3 u = hp[(size_t)g * 16 + lane];                   // self term (eps=0)
    float a0 = blo(u.x), a1 = bhi(u.x), a2 = blo(u.y),
          a3 = bhi(u.y), a4 = blo(u.z), a5 = bhi(u.z);
    int e0 = rowstart[g], e1 = rowstart[g + 1];
    int k = e0;
    for (; k + 4 <= e1; k += 4) {                       // 4 gathers in flight
        int s0 = ecsr[k], s1 = ecsr[k + 1], s2 = ecsr[k + 2], s3 = ecsr[k + 3];
        u3 v0 = hp[(size_t)s0 * 16 + lane];
        u3 v1 = hp[(size_t)s1 * 16 + lane];
        u3 v2 = hp[(size_t)s2 * 16 + lane];
        u3 v3 = hp[(size_t)s3 * 16 + lane];
        a0 += blo(v0.x) + blo(v1.x) + blo(v2.x) + blo(v3.x);
        a1 += bhi(v0.x) + bhi(v1.x) + bhi(v2.x) + bhi(v3.x);
        a2 += blo(v0.y) + blo(v1.y) + blo(v2.y) + blo(v3.y);
        a3 += bhi(v0.y) + bhi(v1.y) + bhi(v2.y) + bhi(v3.y);
        a4 += blo(v0.z) + blo(v1.z) + blo(v2.z) + blo(v3.z);
        a5 += bhi(v0.z) + bhi(v1.z) + bhi(v2.z) + bhi(v3.z);
    }
    for (; k < e1; k++) {
        int s = ecsr[k];
        u3 v = hp[(size_t)s * 16 + lane];
        a0 += blo(v.x); a1 += bhi(v.x); a2 += blo(v.y);
        a3 += bhi(v.y); a4 += blo(v.z); a5 += bhi(v.z);
    }
    union { __hip_bfloat16 hh[6]; u3 uu; } p;
    p.hh[0] = __float2bfloat16(a0); p.hh[1] = __float2bfloat16(a1);
    p.hh[2] = __float2bfloat16(a2); p.hh[3] = __float2bfloat16(a3);
    p.hh[4] = __float2bfloat16(a4); p.hh[5] = __float2bfloat16(a5);
    ((u3*)t16)[(size_t)g * 16 + lane] = p.uu;
}

// ---------------- MFMA MLP: h = relu(t@W1+b1)@W2 + b2 ----------------
// 64 rows/block, 4 waves; wave w owns 16-row band. 6 n-tiles x 3 k-steps per pass.
__global__ __launch_bounds__(256) void k_mlpm(const __hip_bfloat16* __restrict__ t16,
                                              const __hip_bfloat16* __restrict__ w1t,
                                              const float* __restrict__ B1,
                                              const __hip_bfloat16* __restrict__ w2t,
                                              const float* __restrict__ B2,
                                              __hip_bfloat16* __restrict__ h16,
                                              float* __restrict__ out,
                                              int n, int ocol) {
    __shared__ __align__(16) short aT[64 * ASTR];   // activations / y1, bf16
    __shared__ __align__(16) short wS[96 * WSTR];   // current weight, bf16 transposed

    const int tid = threadIdx.x;
    const int row0 = blockIdx.x * 64;
    const int lane = tid & 63;
    const int wv = __builtin_amdgcn_readfirstlane(tid >> 6);
    const int wr0 = wv * 16;                         // wave's row band
    const int quad = lane >> 4;
    const int r = lane & 15;

    // stage 64 rows of t16 (8B chunks) and W1
    {
        const uint2* tsrc = (const uint2*)t16;
        for (int idx = tid; idx < 64 * 24; idx += 256) {
            int rr = idx / 24, c = idx - rr * 24;
            int gr = row0 + rr; if (gr >= n) gr = n - 1;
            *(uint2*)&aT[rr * ASTR + c * 4] = tsrc[(size_t)gr * 24 + c];
        }
        const unsigned* wsrc = (const unsigned*)w1t;
        unsigned* wdst = (unsigned*)wS;
        for (int idx = tid; idx < 96 * WSTR / 2; idx += 256) wdst[idx] = wsrc[idx];
    }
    __syncthreads();

    // A fragments: A[m=r][k=quad*8+j]
    short8 af[3];
    #pragma unroll
    for (int ksi = 0; ksi < 3; ksi++)
        af[ksi] = *(const short8*)&aT[(wr0 + r) * ASTR + ksi * 32 + quad * 8];

    // ---- pass 1 ----
    f32x4v c1[6];
    #pragma unroll
    for (int nt = 0; nt < 6; nt++) {
        f32x4v c = {0.f, 0.f, 0.f, 0.f};
        #pragma unroll
        for (int ksi = 0; ksi < 3; ksi++) {
            short8 bfr = *(const short8*)&wS[(nt * 16 + r) * WSTR + ksi * 32 + quad * 8];
            c = __builtin_amdgcn_mfma_f32_16x16x32_bf16(af[ksi], bfr, c, 0, 0, 0);
        }
        c1[nt] = c;
    }
    __syncthreads();                                 // everyone done reading W1

    // y1 = relu(c + b1) -> bf16 into own band of aT; restage W2
    #pragma unroll
    for (int nt = 0; nt < 6; nt++) {
        float bv = B1[nt * 16 + r];
        #pragma unroll
        for (int i = 0; i < 4; i++) {
            float y = fmaxf(c1[nt][i] + bv, 0.f);
            __hip_bfloat16 hb = __float2bfloat16(y);
            aT[(wr0 + quad * 4 + i) * ASTR + nt * 16 + r] = *(short*)&hb;
        }
    }
    {
        const unsigned* wsrc = (const unsigned*)w2t;
        unsigned* wdst = (unsigned*)wS;
        for (int idx = tid; idx < 96 * WSTR / 2; idx += 256) wdst[idx] = wsrc[idx];
    }
    __syncthreads();

    // ---- pass 2 ----
    short8 af2[3];
    #pragma unroll
    for (int ksi = 0; ksi < 3; ksi++)
        af2[ksi] = *(const short8*)&aT[(wr0 + r) * ASTR + ksi * 32 + quad * 8];

    #pragma unroll
    for (int nt = 0; nt < 6; nt++) {
        f32x4v c = {0.f, 0.f, 0.f, 0.f};
        #pragma unroll
        for (int ksi = 0; ksi < 3; ksi++) {
            short8 bfr = *(const short8*)&wS[(nt * 16 + r) * WSTR + ksi * 32 + quad * 8];
            c = __builtin_amdgcn_mfma_f32_16x16x32_bf16(af2[ksi], bfr, c, 0, 0, 0);
        }
        float bv = B2[nt * 16 + r];
        int col = nt * 16 + r;
        #pragma unroll
        for (int i = 0; i < 4; i++) {
            int gr = row0 + wr0 + quad * 4 + i;
            if (gr < n) {
                float v = c[i] + bv;
                out[(size_t)gr * 384 + ocol + col] = v;
                h16[(size_t)gr * D + col] = __float2bfloat16(v);
            }
        }
    }
}

extern "C" void kernel_launch(void* const* d_in, const int* in_sizes, int n_in,
                              void* d_out, int out_size, void* d_ws, size_t ws_size,
                              hipStream_t stream) {
    const float* x = (const float*)d_in[0];
    const int* ei = (const int*)d_in[1];
    const int n = in_sizes[0] / D;           // 50000
    const int E = in_sizes[1] / 2;           // 800000
    const int* src = ei;
    const int* dst = ei + E;
    float* out = (float*)d_out;

    // workspace layout (byte offsets, all 16B-aligned)
    char* ws = (char*)d_ws;
    __hip_bfloat16* t16  = (__hip_bfloat16*)ws;                  // n*96 halves = 9.6 MB
    __hip_bfloat16* h16  = (__hip_bfloat16*)(ws + 9600000);      // n*96 halves = 9.6 MB
    __hip_bfloat16* wTg  = (__hip_bfloat16*)(ws + 19200000);     // 6*96*104 halves ~ 120 KB
    int*   rowcnt   = (int*)(ws + 19400000);                     // n ints = 200 KB
    int*   rowstart = (int*)(ws + 19600000);                     // n+1 ints
    int*   cursor   = (int*)(ws + 19800016);                     // n ints
    int*   ecsr     = (int*)(ws + 20000064);                     // E ints = 3.2 MB
    int*   bsum     = (int*)(ws + 23200064);                     // <=256 ints
    int*   boff     = (int*)(ws + 23201088);                     // <=256 ints

    // out[:,0:96] = x ; h16 = bf16(x)
    k_copyx<<<(n * 24 + 255) / 256, 256, 0, stream>>>(x, out, h16, n);

    // weights -> bf16 transposed
    k_prep<<<(6 * 9216 + 255) / 256, 256, 0, stream>>>(
        (const float*)d_in[2], (const float*)d_in[4],
        (const float*)d_in[6], (const float*)d_in[8],
        (const float*)d_in[10], (const float*)d_in[12], wTg);

    // direct 1-level CSR build (once; shared by all 3 layers)
    hipMemsetAsync(rowcnt, 0, (size_t)n * sizeof(int), stream);
    k_count<<<2048, 256, 0, stream>>>(dst, rowcnt, E);
    const int NBS = (n + 255) / 256;         // 196
    k_scan_up<<<NBS, 256, 0, stream>>>(rowcnt, rowstart, bsum, n);
    k_scan_mid<<<1, 256, 0, stream>>>(bsum, boff, NBS);
    k_scan_down<<<NBS, 256, 0, stream>>>(rowstart, boff, cursor, n, E);
    k_scatter<<<2048, 256, 0, stream>>>(src, dst, cursor, ecsr, E);

    const int aggr_grid = (n * 16 + 255) / 256;
    const int mlp_grid  = (n + 63) / 64;

    for (int l = 0; l < 3; l++) {
        const float* B1 = (const float*)d_in[3 + 4 * l];
        const float* B2 = (const float*)d_in[5 + 4 * l];
        const __hip_bfloat16* w1t = wTg + (size_t)(2 * l) * (96 * WSTR);
        const __hip_bfloat16* w2t = wTg + (size_t)(2 * l + 1) * (96 * WSTR);
        k_aggr<<<aggr_grid, 256, 0, stream>>>(h16, rowstart, ecsr, t16, n);
        k_mlpm<<<mlp_grid, 256, 0, stream>>>(t16, w1t, B1, w2t, B2, h16, out, n, (l + 1) * D);
    }
}

// Round 3
// 316.760 us; speedup vs baseline: 1.3759x; 1.0214x over previous
//
#include <hip/hip_runtime.h>
#include <hip/hip_bf16.h>

#define D 96
#define ASTR 104       // LDS bf16 row stride (halves): 208B, 16B-aligned, 2-way banks (free)
#define WSTR 104

typedef __attribute__((ext_vector_type(8))) short short8;   // 8 bf16 = 4 VGPRs
typedef __attribute__((ext_vector_type(4))) float f32x4v;   // MFMA accumulator

struct u3 { unsigned x, y, z; };                            // 12B row chunk (dwordx3)

__device__ inline float blo(unsigned u) { return __uint_as_float(u << 16); }
__device__ inline float bhi(unsigned u) { return __uint_as_float(u & 0xffff0000u); }

// ---------------- copy x into out[:, 0:96] and bf16 mirror ----------------
__global__ void k_copyx(const float* __restrict__ x, float* __restrict__ out,
                        __hip_bfloat16* __restrict__ h16, int n) {
    int idx = blockIdx.x * blockDim.x + threadIdx.x;   // n*24 float4s
    if (idx >= n * 24) return;
    int r = idx / 24, c = idx - r * 24;
    float4 v = ((const float4*)x)[r * 24 + c];
    ((float4*)out)[r * 96 + c] = v;
    union { __hip_bfloat16 hh[4]; uint2 u; } p;
    p.hh[0] = __float2bfloat16(v.x); p.hh[1] = __float2bfloat16(v.y);
    p.hh[2] = __float2bfloat16(v.z); p.hh[3] = __float2bfloat16(v.w);
    ((uint2*)h16)[r * 24 + c] = p.u;
}

// ---------------- weight prep: fp32 [k][n] -> bf16 transposed [n][k] stride 104 ----------------
__global__ void k_prep(const float* __restrict__ w10, const float* __restrict__ w20,
                       const float* __restrict__ w11, const float* __restrict__ w21,
                       const float* __restrict__ w12, const float* __restrict__ w22,
                       __hip_bfloat16* __restrict__ wTg) {
    int idx = blockIdx.x * blockDim.x + threadIdx.x;   // 6*9216
    if (idx >= 6 * 9216) return;
    int m = idx / 9216, i = idx - m * 9216;
    int k = i / 96, nn = i - k * 96;
    const float* W;
    switch (m) {
        case 0: W = w10; break; case 1: W = w20; break;
        case 2: W = w11; break; case 3: W = w21; break;
        case 4: W = w12; break; default: W = w22; break;
    }
    wTg[(size_t)m * (96 * WSTR) + nn * WSTR + k] = __float2bfloat16(W[k * 96 + nn]);
}

// ---------------- direct 1-level CSR build ----------------
// per-node in-degree histogram (fire-and-forget atomics, L2-resident counters)
__global__ __launch_bounds__(256) void k_count(const int* __restrict__ dst,
                                               int* __restrict__ cnt, int E) {
    int stride = gridDim.x * 256;
    for (int e = blockIdx.x * 256 + threadIdx.x; e < E; e += stride)
        atomicAdd(&cnt[dst[e]], 1);
}

// hierarchical scan, stage 1: per-block inclusive scan -> exclusive partials + block sums
__global__ __launch_bounds__(256) void k_scan_up(const int* __restrict__ cnt,
                                                 int* __restrict__ excl,
                                                 int* __restrict__ bsum, int n) {
    __shared__ int s[256];
    int t = threadIdx.x, b = blockIdx.x;
    int i = b * 256 + t;
    int v = (i < n) ? cnt[i] : 0;
    s[t] = v;
    __syncthreads();
    for (int off = 1; off < 256; off <<= 1) {
        int u = (t >= off) ? s[t - off] : 0;
        __syncthreads();
        s[t] += u;
        __syncthreads();
    }
    if (i < n) excl[i] = s[t] - v;          // exclusive within block
    if (t == 255) bsum[b] = s[255];         // block total
}

// stage 2: single-block exclusive scan of block sums (nb <= 256)
__global__ __launch_bounds__(256) void k_scan_mid(const int* __restrict__ bsum,
                                                  int* __restrict__ boff, int nb) {
    __shared__ int s[256];
    int t = threadIdx.x;
    int v = (t < nb) ? bsum[t] : 0;
    s[t] = v;
    __syncthreads();
    for (int off = 1; off < 256; off <<= 1) {
        int u = (t >= off) ? s[t - off] : 0;
        __syncthreads();
        s[t] += u;
        __syncthreads();
    }
    if (t < nb) boff[t] = s[t] - v;         // exclusive
}

// stage 3: add block offset in place, duplicate into cursor, set rowstart[n]=E
__global__ __launch_bounds__(256) void k_scan_down(int* __restrict__ rowstart,
                                                   const int* __restrict__ boff,
                                                   int* __restrict__ cursor,
                                                   int n, int E) {
    int b = blockIdx.x, t = threadIdx.x;
    int i = b * 256 + t;
    if (i < n) {
        int v = rowstart[i] + boff[b];
        rowstart[i] = v;
        cursor[i] = v;
    }
    if (i == 0) rowstart[n] = E;
}

// XCD-partitioned scatter: partition p = blockIdx&7 handles dst in [p*psz,(p+1)*psz).
// Consecutive blockIdx round-robin across XCDs, so each partition's 400KB ecsr window
// accumulates full lines in ONE XCD's L2 before writeback (kills 16x write amplification).
__global__ __launch_bounds__(256) void k_scatter(const int* __restrict__ src,
                                                 const int* __restrict__ dst,
                                                 int* __restrict__ cursor,
                                                 int* __restrict__ ecsr,
                                                 int E, int psz) {
    int part = blockIdx.x & 7;
    int lo = part * psz;
    int hi = lo + psz;
    int bi = blockIdx.x >> 3;
    int nb = gridDim.x >> 3;
    int stride = nb * 256;
    for (int e = bi * 256 + threadIdx.x; e < E; e += stride) {
        int d = dst[e];
        if (d >= lo && d < hi) {
            int p = atomicAdd(&cursor[d], 1);
            ecsr[p] = src[e];
        }
    }
}

// ---------------- GIN aggregation (bf16 rows): t[i] = h[i] + sum h[s] ----------------
// 16-lane group per node; lane l holds dwords [3l,3l+3) of the 192B row (dwordx3).
// 100% lane utilization, 4 nodes per wave.
__global__ __launch_bounds__(256) void k_aggr(const __hip_bfloat16* __restrict__ h16,
                                              const int* __restrict__ rowstart,
                                              const int* __restrict__ ecsr,
                                              __hip_bfloat16* __restrict__ t16, int n) {
    int g = (blockIdx.x * 256 + threadIdx.x) >> 4;      // node id
    int lane = threadIdx.x & 15;
    if (g >= n) return;
    const u3* hp = (const u3*)h16;                      // 16 u3 per row
    u3 u = hp[(size_t)g * 16 + lane];                   // self term (eps=0)
    float a0 = blo(u.x), a1 = bhi(u.x), a2 = blo(u.y),
          a3 = bhi(u.y), a4 = blo(u.z), a5 = bhi(u.z);
    int e0 = rowstart[g], e1 = rowstart[g + 1];
    int k = e0;
    for (; k + 4 <= e1; k += 4) {                       // 4 gathers in flight
        int s0 = ecsr[k], s1 = ecsr[k + 1], s2 = ecsr[k + 2], s3 = ecsr[k + 3];
        u3 v0 = hp[(size_t)s0 * 16 + lane];
        u3 v1 = hp[(size_t)s1 * 16 + lane];
        u3 v2 = hp[(size_t)s2 * 16 + lane];
        u3 v3 = hp[(size_t)s3 * 16 + lane];
        a0 += blo(v0.x) + blo(v1.x) + blo(v2.x) + blo(v3.x);
        a1 += bhi(v0.x) + bhi(v1.x) + bhi(v2.x) + bhi(v3.x);
        a2 += blo(v0.y) + blo(v1.y) + blo(v2.y) + blo(v3.y);
        a3 += bhi(v0.y) + bhi(v1.y) + bhi(v2.y) + bhi(v3.y);
        a4 += blo(v0.z) + blo(v1.z) + blo(v2.z) + blo(v3.z);
        a5 += bhi(v0.z) + bhi(v1.z) + bhi(v2.z) + bhi(v3.z);
    }
    for (; k < e1; k++) {
        int s = ecsr[k];
        u3 v = hp[(size_t)s * 16 + lane];
        a0 += blo(v.x); a1 += bhi(v.x); a2 += blo(v.y);
        a3 += bhi(v.y); a4 += blo(v.z); a5 += bhi(v.z);
    }
    union { __hip_bfloat16 hh[6]; u3 uu; } p;
    p.hh[0] = __float2bfloat16(a0); p.hh[1] = __float2bfloat16(a1);
    p.hh[2] = __float2bfloat16(a2); p.hh[3] = __float2bfloat16(a3);
    p.hh[4] = __float2bfloat16(a4); p.hh[5] = __float2bfloat16(a5);
    ((u3*)t16)[(size_t)g * 16 + lane] = p.uu;
}

// ---------------- MFMA MLP: h = relu(t@W1+b1)@W2 + b2 ----------------
// 64 rows/block, 4 waves; wave w owns 16-row band. 6 n-tiles x 3 k-steps per pass.
__global__ __launch_bounds__(256) void k_mlpm(const __hip_bfloat16* __restrict__ t16,
                                              const __hip_bfloat16* __restrict__ w1t,
                                              const float* __restrict__ B1,
                                              const __hip_bfloat16* __restrict__ w2t,
                                              const float* __restrict__ B2,
                                              __hip_bfloat16* __restrict__ h16,
                                              float* __restrict__ out,
                                              int n, int ocol) {
    __shared__ __align__(16) short aT[64 * ASTR];   // activations / y1, bf16
    __shared__ __align__(16) short wS[96 * WSTR];   // current weight, bf16 transposed

    const int tid = threadIdx.x;
    const int row0 = blockIdx.x * 64;
    const int lane = tid & 63;
    const int wv = __builtin_amdgcn_readfirstlane(tid >> 6);
    const int wr0 = wv * 16;                         // wave's row band
    const int quad = lane >> 4;
    const int r = lane & 15;

    // stage 64 rows of t16 (8B chunks) and W1
    {
        const uint2* tsrc = (const uint2*)t16;
        for (int idx = tid; idx < 64 * 24; idx += 256) {
            int rr = idx / 24, c = idx - rr * 24;
            int gr = row0 + rr; if (gr >= n) gr = n - 1;
            *(uint2*)&aT[rr * ASTR + c * 4] = tsrc[(size_t)gr * 24 + c];
        }
        const unsigned* wsrc = (const unsigned*)w1t;
        unsigned* wdst = (unsigned*)wS;
        for (int idx = tid; idx < 96 * WSTR / 2; idx += 256) wdst[idx] = wsrc[idx];
    }
    __syncthreads();

    // A fragments: A[m=r][k=quad*8+j]
    short8 af[3];
    #pragma unroll
    for (int ksi = 0; ksi < 3; ksi++)
        af[ksi] = *(const short8*)&aT[(wr0 + r) * ASTR + ksi * 32 + quad * 8];

    // ---- pass 1 ----
    f32x4v c1[6];
    #pragma unroll
    for (int nt = 0; nt < 6; nt++) {
        f32x4v c = {0.f, 0.f, 0.f, 0.f};
        #pragma unroll
        for (int ksi = 0; ksi < 3; ksi++) {
            short8 bfr = *(const short8*)&wS[(nt * 16 + r) * WSTR + ksi * 32 + quad * 8];
            c = __builtin_amdgcn_mfma_f32_16x16x32_bf16(af[ksi], bfr, c, 0, 0, 0);
        }
        c1[nt] = c;
    }
    __syncthreads();                                 // everyone done reading W1

    // y1 = relu(c + b1) -> bf16 into own band of aT; restage W2
    #pragma unroll
    for (int nt = 0; nt < 6; nt++) {
        float bv = B1[nt * 16 + r];
        #pragma unroll
        for (int i = 0; i < 4; i++) {
            float y = fmaxf(c1[nt][i] + bv, 0.f);
            __hip_bfloat16 hb = __float2bfloat16(y);
            aT[(wr0 + quad * 4 + i) * ASTR + nt * 16 + r] = *(short*)&hb;
        }
    }
    {
        const unsigned* wsrc = (const unsigned*)w2t;
        unsigned* wdst = (unsigned*)wS;
        for (int idx = tid; idx < 96 * WSTR / 2; idx += 256) wdst[idx] = wsrc[idx];
    }
    __syncthreads();

    // ---- pass 2 ----
    short8 af2[3];
    #pragma unroll
    for (int ksi = 0; ksi < 3; ksi++)
        af2[ksi] = *(const short8*)&aT[(wr0 + r) * ASTR + ksi * 32 + quad * 8];

    #pragma unroll
    for (int nt = 0; nt < 6; nt++) {
        f32x4v c = {0.f, 0.f, 0.f, 0.f};
        #pragma unroll
        for (int ksi = 0; ksi < 3; ksi++) {
            short8 bfr = *(const short8*)&wS[(nt * 16 + r) * WSTR + ksi * 32 + quad * 8];
            c = __builtin_amdgcn_mfma_f32_16x16x32_bf16(af2[ksi], bfr, c, 0, 0, 0);
        }
        float bv = B2[nt * 16 + r];
        int col = nt * 16 + r;
        #pragma unroll
        for (int i = 0; i < 4; i++) {
            int gr = row0 + wr0 + quad * 4 + i;
            if (gr < n) {
                float v = c[i] + bv;
                out[(size_t)gr * 384 + ocol + col] = v;
                h16[(size_t)gr * D + col] = __float2bfloat16(v);
            }
        }
    }
}

extern "C" void kernel_launch(void* const* d_in, const int* in_sizes, int n_in,
                              void* d_out, int out_size, void* d_ws, size_t ws_size,
                              hipStream_t stream) {
    const float* x = (const float*)d_in[0];
    const int* ei = (const int*)d_in[1];
    const int n = in_sizes[0] / D;           // 50000
    const int E = in_sizes[1] / 2;           // 800000
    const int* src = ei;
    const int* dst = ei + E;
    float* out = (float*)d_out;

    // workspace layout (byte offsets, all 16B-aligned)
    char* ws = (char*)d_ws;
    __hip_bfloat16* t16  = (__hip_bfloat16*)ws;                  // n*96 halves = 9.6 MB
    __hip_bfloat16* h16  = (__hip_bfloat16*)(ws + 9600000);      // n*96 halves = 9.6 MB
    __hip_bfloat16* wTg  = (__hip_bfloat16*)(ws + 19200000);     // 6*96*104 halves ~ 120 KB
    int*   rowcnt   = (int*)(ws + 19400000);                     // n ints = 200 KB
    int*   rowstart = (int*)(ws + 19600000);                     // n+1 ints
    int*   cursor   = (int*)(ws + 19800016);                     // n ints
    int*   ecsr     = (int*)(ws + 20000064);                     // E ints = 3.2 MB
    int*   bsum     = (int*)(ws + 23200064);                     // <=256 ints
    int*   boff     = (int*)(ws + 23201088);                     // <=256 ints

    // out[:,0:96] = x ; h16 = bf16(x)
    k_copyx<<<(n * 24 + 255) / 256, 256, 0, stream>>>(x, out, h16, n);

    // weights -> bf16 transposed
    k_prep<<<(6 * 9216 + 255) / 256, 256, 0, stream>>>(
        (const float*)d_in[2], (const float*)d_in[4],
        (const float*)d_in[6], (const float*)d_in[8],
        (const float*)d_in[10], (const float*)d_in[12], wTg);

    // direct 1-level CSR build (once; shared by all 3 layers)
    hipMemsetAsync(rowcnt, 0, (size_t)n * sizeof(int), stream);
    k_count<<<2048, 256, 0, stream>>>(dst, rowcnt, E);
    const int NBS = (n + 255) / 256;         // 196
    k_scan_up<<<NBS, 256, 0, stream>>>(rowcnt, rowstart, bsum, n);
    k_scan_mid<<<1, 256, 0, stream>>>(bsum, boff, NBS);
    k_scan_down<<<NBS, 256, 0, stream>>>(rowstart, boff, cursor, n, E);
    const int psz = (n + 7) / 8;             // 6250
    k_scatter<<<2048, 256, 0, stream>>>(src, dst, cursor, ecsr, E, psz);

    const int aggr_grid = (n * 16 + 255) / 256;
    const int mlp_grid  = (n + 63) / 64;

    for (int l = 0; l < 3; l++) {
        const float* B1 = (const float*)d_in[3 + 4 * l];
        const float* B2 = (const float*)d_in[5 + 4 * l];
        const __hip_bfloat16* w1t = wTg + (size_t)(2 * l) * (96 * WSTR);
        const __hip_bfloat16* w2t = wTg + (size_t)(2 * l + 1) * (96 * WSTR);
        k_aggr<<<aggr_grid, 256, 0, stream>>>(h16, rowstart, ecsr, t16, n);
        k_mlpm<<<mlp_grid, 256, 0, stream>>>(t16, w1t, B1, w2t, B2, h16, out, n, (l + 1) * D);
    }
}

// Round 4
// 292.963 us; speedup vs baseline: 1.4876x; 1.0812x over previous
//
#include <hip/hip_runtime.h>
#include <hip/hip_bf16.h>

#define D 96
#define ASTR 104       // LDS bf16 row stride (halves): 208B, 16B-aligned, 2-way banks (free)
#define WSTR 104

typedef __attribute__((ext_vector_type(8))) short short8;   // 8 bf16 = 4 VGPRs
typedef __attribute__((ext_vector_type(4))) float f32x4v;   // MFMA accumulator

struct u3 { unsigned x, y, z; };                            // 12B row chunk (dwordx3)

__device__ inline float blo(unsigned u) { return __uint_as_float(u << 16); }
__device__ inline float bhi(unsigned u) { return __uint_as_float(u & 0xffff0000u); }

// ---------------- copy x into out[:, 0:96] and bf16 mirror ----------------
__global__ void k_copyx(const float* __restrict__ x, float* __restrict__ out,
                        __hip_bfloat16* __restrict__ h16, int n) {
    int idx = blockIdx.x * blockDim.x + threadIdx.x;   // n*24 float4s
    if (idx >= n * 24) return;
    int r = idx / 24, c = idx - r * 24;
    float4 v = ((const float4*)x)[r * 24 + c];
    ((float4*)out)[r * 96 + c] = v;
    union { __hip_bfloat16 hh[4]; uint2 u; } p;
    p.hh[0] = __float2bfloat16(v.x); p.hh[1] = __float2bfloat16(v.y);
    p.hh[2] = __float2bfloat16(v.z); p.hh[3] = __float2bfloat16(v.w);
    ((uint2*)h16)[r * 24 + c] = p.u;
}

// ---------------- weight prep: fp32 [k][n] -> bf16 transposed [n][k] stride 104 ----------------
__global__ void k_prep(const float* __restrict__ w10, const float* __restrict__ w20,
                       const float* __restrict__ w11, const float* __restrict__ w21,
                       const float* __restrict__ w12, const float* __restrict__ w22,
                       __hip_bfloat16* __restrict__ wTg) {
    int idx = blockIdx.x * blockDim.x + threadIdx.x;   // 6*9216
    if (idx >= 6 * 9216) return;
    int m = idx / 9216, i = idx - m * 9216;
    int k = i / 96, nn = i - k * 96;
    const float* W;
    switch (m) {
        case 0: W = w10; break; case 1: W = w20; break;
        case 2: W = w11; break; case 3: W = w21; break;
        case 4: W = w12; break; default: W = w22; break;
    }
    wTg[(size_t)m * (96 * WSTR) + nn * WSTR + k] = __float2bfloat16(W[k * 96 + nn]);
}

// ---------------- direct 1-level CSR build ----------------
// per-node in-degree histogram; the atomic's RETURN VALUE is the edge's rank
// within its destination segment (makes the scatter pass atomic-free)
__global__ __launch_bounds__(256) void k_count(const int* __restrict__ dst,
                                               int* __restrict__ cnt,
                                               int* __restrict__ rank, int E) {
    int stride = gridDim.x * 256;
    for (int e = blockIdx.x * 256 + threadIdx.x; e < E; e += stride)
        rank[e] = atomicAdd(&cnt[dst[e]], 1);
}

// hierarchical scan, stage 1: per-block inclusive scan -> exclusive partials + block sums
__global__ __launch_bounds__(256) void k_scan_up(const int* __restrict__ cnt,
                                                 int* __restrict__ excl,
                                                 int* __restrict__ bsum, int n) {
    __shared__ int s[256];
    int t = threadIdx.x, b = blockIdx.x;
    int i = b * 256 + t;
    int v = (i < n) ? cnt[i] : 0;
    s[t] = v;
    __syncthreads();
    for (int off = 1; off < 256; off <<= 1) {
        int u = (t >= off) ? s[t - off] : 0;
        __syncthreads();
        s[t] += u;
        __syncthreads();
    }
    if (i < n) excl[i] = s[t] - v;          // exclusive within block
    if (t == 255) bsum[b] = s[255];         // block total
}

// stage 2: single-block exclusive scan of block sums (nb <= 256)
__global__ __launch_bounds__(256) void k_scan_mid(const int* __restrict__ bsum,
                                                  int* __restrict__ boff, int nb) {
    __shared__ int s[256];
    int t = threadIdx.x;
    int v = (t < nb) ? bsum[t] : 0;
    s[t] = v;
    __syncthreads();
    for (int off = 1; off < 256; off <<= 1) {
        int u = (t >= off) ? s[t - off] : 0;
        __syncthreads();
        s[t] += u;
        __syncthreads();
    }
    if (t < nb) boff[t] = s[t] - v;         // exclusive
}

// stage 3: add block offset in place, set rowstart[n]=E
__global__ __launch_bounds__(256) void k_scan_down(int* __restrict__ rowstart,
                                                   const int* __restrict__ boff,
                                                   int n, int E) {
    int b = blockIdx.x, t = threadIdx.x;
    int i = b * 256 + t;
    if (i < n) rowstart[i] += boff[b];
    if (i == 0) rowstart[n] = E;
}

// atomic-free XCD-partitioned scatter: partition p = blockIdx&7 handles dst in
// [p*psz,(p+1)*psz). Each partition's 400KB ecsr window write-combines in one
// XCD's L2; position = rowstart[d] + precomputed rank (no cursor, no RMW).
__global__ __launch_bounds__(256) void k_scatter(const int* __restrict__ src,
                                                 const int* __restrict__ dst,
                                                 const int* __restrict__ rank,
                                                 const int* __restrict__ rowstart,
                                                 int* __restrict__ ecsr,
                                                 int E, int psz) {
    int part = blockIdx.x & 7;
    int lo = part * psz;
    int hi = lo + psz;
    int bi = blockIdx.x >> 3;
    int nb = gridDim.x >> 3;
    int stride = nb * 256;
    for (int e = bi * 256 + threadIdx.x; e < E; e += stride) {
        int d = dst[e];
        if (d >= lo && d < hi)
            ecsr[rowstart[d] + rank[e]] = src[e];
    }
}

// ---------------- GIN aggregation (bf16 rows): t[i] = h[i] + sum h[s] ----------------
// 16-lane group per node; lane l holds dwords [3l,3l+3) of the 192B row (dwordx3).
// 8 gathers in flight for memory-level parallelism.
__global__ __launch_bounds__(256) void k_aggr(const __hip_bfloat16* __restrict__ h16,
                                              const int* __restrict__ rowstart,
                                              const int* __restrict__ ecsr,
                                              __hip_bfloat16* __restrict__ t16, int n) {
    int g = (blockIdx.x * 256 + threadIdx.x) >> 4;      // node id
    int lane = threadIdx.x & 15;
    if (g >= n) return;
    const u3* hp = (const u3*)h16;                      // 16 u3 per row
    u3 u = hp[(size_t)g * 16 + lane];                   // self term (eps=0)
    float a0 = blo(u.x), a1 = bhi(u.x), a2 = blo(u.y),
          a3 = bhi(u.y), a4 = blo(u.z), a5 = bhi(u.z);
    int e0 = rowstart[g], e1 = rowstart[g + 1];
    int k = e0;
    for (; k + 8 <= e1; k += 8) {                       // 8 gathers in flight
        int s0 = ecsr[k],     s1 = ecsr[k + 1], s2 = ecsr[k + 2], s3 = ecsr[k + 3];
        int s4 = ecsr[k + 4], s5 = ecsr[k + 5], s6 = ecsr[k + 6], s7 = ecsr[k + 7];
        u3 v0 = hp[(size_t)s0 * 16 + lane];
        u3 v1 = hp[(size_t)s1 * 16 + lane];
        u3 v2 = hp[(size_t)s2 * 16 + lane];
        u3 v3 = hp[(size_t)s3 * 16 + lane];
        u3 v4 = hp[(size_t)s4 * 16 + lane];
        u3 v5 = hp[(size_t)s5 * 16 + lane];
        u3 v6 = hp[(size_t)s6 * 16 + lane];
        u3 v7 = hp[(size_t)s7 * 16 + lane];
        a0 += blo(v0.x) + blo(v1.x) + blo(v2.x) + blo(v3.x)
            + blo(v4.x) + blo(v5.x) + blo(v6.x) + blo(v7.x);
        a1 += bhi(v0.x) + bhi(v1.x) + bhi(v2.x) + bhi(v3.x)
            + bhi(v4.x) + bhi(v5.x) + bhi(v6.x) + bhi(v7.x);
        a2 += blo(v0.y) + blo(v1.y) + blo(v2.y) + blo(v3.y)
            + blo(v4.y) + blo(v5.y) + blo(v6.y) + blo(v7.y);
        a3 += bhi(v0.y) + bhi(v1.y) + bhi(v2.y) + bhi(v3.y)
            + bhi(v4.y) + bhi(v5.y) + bhi(v6.y) + bhi(v7.y);
        a4 += blo(v0.z) + blo(v1.z) + blo(v2.z) + blo(v3.z)
            + blo(v4.z) + blo(v5.z) + blo(v6.z) + blo(v7.z);
        a5 += bhi(v0.z) + bhi(v1.z) + bhi(v2.z) + bhi(v3.z)
            + bhi(v4.z) + bhi(v5.z) + bhi(v6.z) + bhi(v7.z);
    }
    for (; k + 4 <= e1; k += 4) {
        int s0 = ecsr[k], s1 = ecsr[k + 1], s2 = ecsr[k + 2], s3 = ecsr[k + 3];
        u3 v0 = hp[(size_t)s0 * 16 + lane];
        u3 v1 = hp[(size_t)s1 * 16 + lane];
        u3 v2 = hp[(size_t)s2 * 16 + lane];
        u3 v3 = hp[(size_t)s3 * 16 + lane];
        a0 += blo(v0.x) + blo(v1.x) + blo(v2.x) + blo(v3.x);
        a1 += bhi(v0.x) + bhi(v1.x) + bhi(v2.x) + bhi(v3.x);
        a2 += blo(v0.y) + blo(v1.y) + blo(v2.y) + blo(v3.y);
        a3 += bhi(v0.y) + bhi(v1.y) + bhi(v2.y) + bhi(v3.y);
        a4 += blo(v0.z) + blo(v1.z) + blo(v2.z) + blo(v3.z);
        a5 += bhi(v0.z) + bhi(v1.z) + bhi(v2.z) + bhi(v3.z);
    }
    for (; k < e1; k++) {
        int s = ecsr[k];
        u3 v = hp[(size_t)s * 16 + lane];
        a0 += blo(v.x); a1 += bhi(v.x); a2 += blo(v.y);
        a3 += bhi(v.y); a4 += blo(v.z); a5 += bhi(v.z);
    }
    union { __hip_bfloat16 hh[6]; u3 uu; } p;
    p.hh[0] = __float2bfloat16(a0); p.hh[1] = __float2bfloat16(a1);
    p.hh[2] = __float2bfloat16(a2); p.hh[3] = __float2bfloat16(a3);
    p.hh[4] = __float2bfloat16(a4); p.hh[5] = __float2bfloat16(a5);
    ((u3*)t16)[(size_t)g * 16 + lane] = p.uu;
}

// ---------------- MFMA MLP: h = relu(t@W1+b1)@W2 + b2 ----------------
// 64 rows/block, 4 waves; wave w owns 16-row band. 6 n-tiles x 3 k-steps per pass.
__global__ __launch_bounds__(256) void k_mlpm(const __hip_bfloat16* __restrict__ t16,
                                              const __hip_bfloat16* __restrict__ w1t,
                                              const float* __restrict__ B1,
                                              const __hip_bfloat16* __restrict__ w2t,
                                              const float* __restrict__ B2,
                                              __hip_bfloat16* __restrict__ h16,
                                              float* __restrict__ out,
                                              int n, int ocol) {
    __shared__ __align__(16) short aT[64 * ASTR];   // activations / y1, bf16
    __shared__ __align__(16) short wS[96 * WSTR];   // current weight, bf16 transposed

    const int tid = threadIdx.x;
    const int row0 = blockIdx.x * 64;
    const int lane = tid & 63;
    const int wv = __builtin_amdgcn_readfirstlane(tid >> 6);
    const int wr0 = wv * 16;                         // wave's row band
    const int quad = lane >> 4;
    const int r = lane & 15;

    // stage 64 rows of t16 (8B chunks) and W1
    {
        const uint2* tsrc = (const uint2*)t16;
        for (int idx = tid; idx < 64 * 24; idx += 256) {
            int rr = idx / 24, c = idx - rr * 24;
            int gr = row0 + rr; if (gr >= n) gr = n - 1;
            *(uint2*)&aT[rr * ASTR + c * 4] = tsrc[(size_t)gr * 24 + c];
        }
        const unsigned* wsrc = (const unsigned*)w1t;
        unsigned* wdst = (unsigned*)wS;
        for (int idx = tid; idx < 96 * WSTR / 2; idx += 256) wdst[idx] = wsrc[idx];
    }
    __syncthreads();

    // A fragments: A[m=r][k=quad*8+j]
    short8 af[3];
    #pragma unroll
    for (int ksi = 0; ksi < 3; ksi++)
        af[ksi] = *(const short8*)&aT[(wr0 + r) * ASTR + ksi * 32 + quad * 8];

    // ---- pass 1 ----
    f32x4v c1[6];
    #pragma unroll
    for (int nt = 0; nt < 6; nt++) {
        f32x4v c = {0.f, 0.f, 0.f, 0.f};
        #pragma unroll
        for (int ksi = 0; ksi < 3; ksi++) {
            short8 bfr = *(const short8*)&wS[(nt * 16 + r) * WSTR + ksi * 32 + quad * 8];
            c = __builtin_amdgcn_mfma_f32_16x16x32_bf16(af[ksi], bfr, c, 0, 0, 0);
        }
        c1[nt] = c;
    }
    __syncthreads();                                 // everyone done reading W1

    // y1 = relu(c + b1) -> bf16 into own band of aT; restage W2
    #pragma unroll
    for (int nt = 0; nt < 6; nt++) {
        float bv = B1[nt * 16 + r];
        #pragma unroll
        for (int i = 0; i < 4; i++) {
            float y = fmaxf(c1[nt][i] + bv, 0.f);
            __hip_bfloat16 hb = __float2bfloat16(y);
            aT[(wr0 + quad * 4 + i) * ASTR + nt * 16 + r] = *(short*)&hb;
        }
    }
    {
        const unsigned* wsrc = (const unsigned*)w2t;
        unsigned* wdst = (unsigned*)wS;
        for (int idx = tid; idx < 96 * WSTR / 2; idx += 256) wdst[idx] = wsrc[idx];
    }
    __syncthreads();

    // ---- pass 2 ----
    short8 af2[3];
    #pragma unroll
    for (int ksi = 0; ksi < 3; ksi++)
        af2[ksi] = *(const short8*)&aT[(wr0 + r) * ASTR + ksi * 32 + quad * 8];

    #pragma unroll
    for (int nt = 0; nt < 6; nt++) {
        f32x4v c = {0.f, 0.f, 0.f, 0.f};
        #pragma unroll
        for (int ksi = 0; ksi < 3; ksi++) {
            short8 bfr = *(const short8*)&wS[(nt * 16 + r) * WSTR + ksi * 32 + quad * 8];
            c = __builtin_amdgcn_mfma_f32_16x16x32_bf16(af2[ksi], bfr, c, 0, 0, 0);
        }
        float bv = B2[nt * 16 + r];
        int col = nt * 16 + r;
        #pragma unroll
        for (int i = 0; i < 4; i++) {
            int gr = row0 + wr0 + quad * 4 + i;
            if (gr < n) {
                float v = c[i] + bv;
                out[(size_t)gr * 384 + ocol + col] = v;
                h16[(size_t)gr * D + col] = __float2bfloat16(v);
            }
        }
    }
}

extern "C" void kernel_launch(void* const* d_in, const int* in_sizes, int n_in,
                              void* d_out, int out_size, void* d_ws, size_t ws_size,
                              hipStream_t stream) {
    const float* x = (const float*)d_in[0];
    const int* ei = (const int*)d_in[1];
    const int n = in_sizes[0] / D;           // 50000
    const int E = in_sizes[1] / 2;           // 800000
    const int* src = ei;
    const int* dst = ei + E;
    float* out = (float*)d_out;

    // workspace layout (byte offsets, all 16B-aligned)
    char* ws = (char*)d_ws;
    __hip_bfloat16* t16  = (__hip_bfloat16*)ws;                  // n*96 halves = 9.6 MB
    __hip_bfloat16* h16  = (__hip_bfloat16*)(ws + 9600000);      // n*96 halves = 9.6 MB
    __hip_bfloat16* wTg  = (__hip_bfloat16*)(ws + 19200000);     // 6*96*104 halves ~ 120 KB
    int*   rowcnt   = (int*)(ws + 19400000);                     // n ints = 200 KB
    int*   rowstart = (int*)(ws + 19600000);                     // n+1 ints
    int*   rank     = (int*)(ws + 19800016);                     // E ints = 3.2 MB
    int*   ecsr     = (int*)(ws + 23000064);                     // E ints = 3.2 MB
    int*   bsum     = (int*)(ws + 26200064);                     // <=256 ints
    int*   boff     = (int*)(ws + 26201088);                     // <=256 ints

    // out[:,0:96] = x ; h16 = bf16(x)
    k_copyx<<<(n * 24 + 255) / 256, 256, 0, stream>>>(x, out, h16, n);

    // weights -> bf16 transposed
    k_prep<<<(6 * 9216 + 255) / 256, 256, 0, stream>>>(
        (const float*)d_in[2], (const float*)d_in[4],
        (const float*)d_in[6], (const float*)d_in[8],
        (const float*)d_in[10], (const float*)d_in[12], wTg);

    // direct 1-level CSR build (once; shared by all 3 layers)
    hipMemsetAsync(rowcnt, 0, (size_t)n * sizeof(int), stream);
    k_count<<<2048, 256, 0, stream>>>(dst, rowcnt, rank, E);
    const int NBS = (n + 255) / 256;         // 196
    k_scan_up<<<NBS, 256, 0, stream>>>(rowcnt, rowstart, bsum, n);
    k_scan_mid<<<1, 256, 0, stream>>>(bsum, boff, NBS);
    k_scan_down<<<NBS, 256, 0, stream>>>(rowstart, boff, n, E);
    const int psz = (n + 7) / 8;             // 6250
    k_scatter<<<2048, 256, 0, stream>>>(src, dst, rank, rowstart, ecsr, E, psz);

    const int aggr_grid = (n * 16 + 255) / 256;
    const int mlp_grid  = (n + 63) / 64;

    for (int l = 0; l < 3; l++) {
        const float* B1 = (const float*)d_in[3 + 4 * l];
        const float* B2 = (const float*)d_in[5 + 4 * l];
        const __hip_bfloat16* w1t = wTg + (size_t)(2 * l) * (96 * WSTR);
        const __hip_bfloat16* w2t = wTg + (size_t)(2 * l + 1) * (96 * WSTR);
        k_aggr<<<aggr_grid, 256, 0, stream>>>(h16, rowstart, ecsr, t16, n);
        k_mlpm<<<mlp_grid, 256, 0, stream>>>(t16, w1t, B1, w2t, B2, h16, out, n, (l + 1) * D);
    }
}

// Round 5
// 279.073 us; speedup vs baseline: 1.5617x; 1.0498x over previous
//
#include <hip/hip_runtime.h>
#include <hip/hip_bf16.h>

#define D 96
#define ASTR 104       // LDS bf16 row stride (halves): 208B, 16B-aligned, 2-way banks (free)
#define WSTR 104

typedef __attribute__((ext_vector_type(8))) short short8;   // 8 bf16 = 4 VGPRs
typedef __attribute__((ext_vector_type(4))) float f32x4v;   // MFMA accumulator

struct u3 { unsigned x, y, z; };                            // 12B row chunk (dwordx3)

__device__ inline float blo(unsigned u) { return __uint_as_float(u << 16); }
__device__ inline float bhi(unsigned u) { return __uint_as_float(u & 0xffff0000u); }

// ---------------- copy x into out[:, 0:96] and bf16 mirror ----------------
__global__ void k_copyx(const float* __restrict__ x, float* __restrict__ out,
                        __hip_bfloat16* __restrict__ h16, int n) {
    int idx = blockIdx.x * blockDim.x + threadIdx.x;   // n*24 float4s
    if (idx >= n * 24) return;
    int r = idx / 24, c = idx - r * 24;
    float4 v = ((const float4*)x)[r * 24 + c];
    ((float4*)out)[r * 96 + c] = v;
    union { __hip_bfloat16 hh[4]; uint2 u; } p;
    p.hh[0] = __float2bfloat16(v.x); p.hh[1] = __float2bfloat16(v.y);
    p.hh[2] = __float2bfloat16(v.z); p.hh[3] = __float2bfloat16(v.w);
    ((uint2*)h16)[r * 24 + c] = p.u;
}

// ---------------- weight prep: fp32 [k][n] -> bf16 transposed [n][k] stride 104 ----------------
__global__ void k_prep(const float* __restrict__ w10, const float* __restrict__ w20,
                       const float* __restrict__ w11, const float* __restrict__ w21,
                       const float* __restrict__ w12, const float* __restrict__ w22,
                       __hip_bfloat16* __restrict__ wTg) {
    int idx = blockIdx.x * blockDim.x + threadIdx.x;   // 6*9216
    if (idx >= 6 * 9216) return;
    int m = idx / 9216, i = idx - m * 9216;
    int k = i / 96, nn = i - k * 96;
    const float* W;
    switch (m) {
        case 0: W = w10; break; case 1: W = w20; break;
        case 2: W = w11; break; case 3: W = w21; break;
        case 4: W = w12; break; default: W = w22; break;
    }
    wTg[(size_t)m * (96 * WSTR) + nn * WSTR + k] = __float2bfloat16(W[k * 96 + nn]);
}

// ---------------- direct 1-level CSR build ----------------
// per-node in-degree histogram; the atomic's RETURN VALUE is the edge's rank
// within its destination segment (makes the scatter pass atomic-free)
__global__ __launch_bounds__(256) void k_count(const int* __restrict__ dst,
                                               int* __restrict__ cnt,
                                               unsigned short* __restrict__ rank, int E) {
    int stride = gridDim.x * 256;
    for (int e = blockIdx.x * 256 + threadIdx.x; e < E; e += stride)
        rank[e] = (unsigned short)atomicAdd(&cnt[dst[e]], 1);
}

// hierarchical scan, stage 1: per-block inclusive scan -> exclusive partials + block sums
__global__ __launch_bounds__(256) void k_scan_up(const int* __restrict__ cnt,
                                                 int* __restrict__ excl,
                                                 int* __restrict__ bsum, int n) {
    __shared__ int s[256];
    int t = threadIdx.x, b = blockIdx.x;
    int i = b * 256 + t;
    int v = (i < n) ? cnt[i] : 0;
    s[t] = v;
    __syncthreads();
    for (int off = 1; off < 256; off <<= 1) {
        int u = (t >= off) ? s[t - off] : 0;
        __syncthreads();
        s[t] += u;
        __syncthreads();
    }
    if (i < n) excl[i] = s[t] - v;          // exclusive within block
    if (t == 255) bsum[b] = s[255];         // block total
}

// stage 2: single-block exclusive scan of block sums (nb <= 256)
__global__ __launch_bounds__(256) void k_scan_mid(const int* __restrict__ bsum,
                                                  int* __restrict__ boff, int nb) {
    __shared__ int s[256];
    int t = threadIdx.x;
    int v = (t < nb) ? bsum[t] : 0;
    s[t] = v;
    __syncthreads();
    for (int off = 1; off < 256; off <<= 1) {
        int u = (t >= off) ? s[t - off] : 0;
        __syncthreads();
        s[t] += u;
        __syncthreads();
    }
    if (t < nb) boff[t] = s[t] - v;         // exclusive
}

// stage 3: add block offset in place, set rowstart[n]=E
__global__ __launch_bounds__(256) void k_scan_down(int* __restrict__ rowstart,
                                                   const int* __restrict__ boff,
                                                   int n, int E) {
    int b = blockIdx.x, t = threadIdx.x;
    int i = b * 256 + t;
    if (i < n) rowstart[i] += boff[b];
    if (i == 0) rowstart[n] = E;
}

// atomic-free XCD-partitioned scatter: partition p = blockIdx&7 handles dst in
// [p*psz,(p+1)*psz). Each partition's ~200KB ecsr window write-combines in one
// XCD's L2; position = rowstart[d] + precomputed rank (no cursor, no RMW).
__global__ __launch_bounds__(256) void k_scatter(const int* __restrict__ src,
                                                 const int* __restrict__ dst,
                                                 const unsigned short* __restrict__ rank,
                                                 const int* __restrict__ rowstart,
                                                 unsigned short* __restrict__ ecsr,
                                                 int E, int psz) {
    int part = blockIdx.x & 7;
    int lo = part * psz;
    int hi = lo + psz;
    int bi = blockIdx.x >> 3;
    int nb = gridDim.x >> 3;
    int stride = nb * 256;
    for (int e = bi * 256 + threadIdx.x; e < E; e += stride) {
        int d = dst[e];
        if (d >= lo && d < hi)
            ecsr[rowstart[d] + (int)rank[e]] = (unsigned short)src[e];
    }
}

// ---------------- fused layer: aggregate into LDS, then MFMA MLP ----------------
// 64 rows/block, 256 threads. Aggregation: 16 node-groups of 16 lanes, each group
// does 4 nodes; aggregated bf16 row written straight into aT (no t16 round-trip).
// Then: h = relu(t@W1+b1)@W2 + b2 via two MFMA passes (6 n-tiles x 3 k-steps).
// hin/hout ping-pong: blocks gather random rows of hin while writing only hout.
__global__ __launch_bounds__(256) void k_fused(const __hip_bfloat16* __restrict__ hin,
                                               const int* __restrict__ rowstart,
                                               const unsigned short* __restrict__ ecsr,
                                               const __hip_bfloat16* __restrict__ w1t,
                                               const float* __restrict__ B1,
                                               const __hip_bfloat16* __restrict__ w2t,
                                               const float* __restrict__ B2,
                                               __hip_bfloat16* __restrict__ hout,
                                               float* __restrict__ out,
                                               int n, int ocol) {
    __shared__ __align__(16) short aT[64 * ASTR];   // aggregated rows / y1, bf16
    __shared__ __align__(16) short wS[96 * WSTR];   // current weight, bf16 transposed

    const int tid = threadIdx.x;
    const int row0 = blockIdx.x * 64;
    const int lane = tid & 63;
    const int wv = __builtin_amdgcn_readfirstlane(tid >> 6);
    const int wr0 = wv * 16;                         // wave's row band
    const int quad = lane >> 4;
    const int r = lane & 15;

    // stage W1 (global loads issue first, land under the gather latency)
    {
        const unsigned* wsrc = (const unsigned*)w1t;
        unsigned* wdst = (unsigned*)wS;
        for (int idx = tid; idx < 96 * WSTR / 2; idx += 256) wdst[idx] = wsrc[idx];
    }

    // ---- aggregation phase: t[i] = h[i] + sum_j h[src_j], straight into aT ----
    {
        const int ng = tid >> 4;                    // node-group 0..15
        const int gl = tid & 15;                    // lane within group
        const u3* hp = (const u3*)hin;              // 16 u3 per 192B row
        #pragma unroll
        for (int it = 0; it < 4; it++) {
            int rr = ng + it * 16;                  // local row 0..63
            int gr = row0 + rr; if (gr >= n) gr = n - 1;
            u3 u = hp[(size_t)gr * 16 + gl];        // self term (eps=0)
            float a0 = blo(u.x), a1 = bhi(u.x), a2 = blo(u.y),
                  a3 = bhi(u.y), a4 = blo(u.z), a5 = bhi(u.z);
            int e0 = rowstart[gr], e1 = rowstart[gr + 1];
            int k = e0;
            for (; k + 8 <= e1; k += 8) {           // 8 gathers in flight
                int s0 = ecsr[k],     s1 = ecsr[k + 1], s2 = ecsr[k + 2], s3 = ecsr[k + 3];
                int s4 = ecsr[k + 4], s5 = ecsr[k + 5], s6 = ecsr[k + 6], s7 = ecsr[k + 7];
                u3 v0 = hp[(size_t)s0 * 16 + gl];
                u3 v1 = hp[(size_t)s1 * 16 + gl];
                u3 v2 = hp[(size_t)s2 * 16 + gl];
                u3 v3 = hp[(size_t)s3 * 16 + gl];
                u3 v4 = hp[(size_t)s4 * 16 + gl];
                u3 v5 = hp[(size_t)s5 * 16 + gl];
                u3 v6 = hp[(size_t)s6 * 16 + gl];
                u3 v7 = hp[(size_t)s7 * 16 + gl];
                a0 += blo(v0.x) + blo(v1.x) + blo(v2.x) + blo(v3.x)
                    + blo(v4.x) + blo(v5.x) + blo(v6.x) + blo(v7.x);
                a1 += bhi(v0.x) + bhi(v1.x) + bhi(v2.x) + bhi(v3.x)
                    + bhi(v4.x) + bhi(v5.x) + bhi(v6.x) + bhi(v7.x);
                a2 += blo(v0.y) + blo(v1.y) + blo(v2.y) + blo(v3.y)
                    + blo(v4.y) + blo(v5.y) + blo(v6.y) + blo(v7.y);
                a3 += bhi(v0.y) + bhi(v1.y) + bhi(v2.y) + bhi(v3.y)
                    + bhi(v4.y) + bhi(v5.y) + bhi(v6.y) + bhi(v7.y);
                a4 += blo(v0.z) + blo(v1.z) + blo(v2.z) + blo(v3.z)
                    + blo(v4.z) + blo(v5.z) + blo(v6.z) + blo(v7.z);
                a5 += bhi(v0.z) + bhi(v1.z) + bhi(v2.z) + bhi(v3.z)
                    + bhi(v4.z) + bhi(v5.z) + bhi(v6.z) + bhi(v7.z);
            }
            for (; k + 4 <= e1; k += 4) {
                int s0 = ecsr[k], s1 = ecsr[k + 1], s2 = ecsr[k + 2], s3 = ecsr[k + 3];
                u3 v0 = hp[(size_t)s0 * 16 + gl];
                u3 v1 = hp[(size_t)s1 * 16 + gl];
                u3 v2 = hp[(size_t)s2 * 16 + gl];
                u3 v3 = hp[(size_t)s3 * 16 + gl];
                a0 += blo(v0.x) + blo(v1.x) + blo(v2.x) + blo(v3.x);
                a1 += bhi(v0.x) + bhi(v1.x) + bhi(v2.x) + bhi(v3.x);
                a2 += blo(v0.y) + blo(v1.y) + blo(v2.y) + blo(v3.y);
                a3 += bhi(v0.y) + bhi(v1.y) + bhi(v2.y) + bhi(v3.y);
                a4 += blo(v0.z) + blo(v1.z) + blo(v2.z) + blo(v3.z);
                a5 += bhi(v0.z) + bhi(v1.z) + bhi(v2.z) + bhi(v3.z);
            }
            for (; k < e1; k++) {
                int s = ecsr[k];
                u3 v = hp[(size_t)s * 16 + gl];
                a0 += blo(v.x); a1 += bhi(v.x); a2 += blo(v.y);
                a3 += bhi(v.y); a4 += blo(v.z); a5 += bhi(v.z);
            }
            union { __hip_bfloat16 hh[6]; u3 uu; } p;
            p.hh[0] = __float2bfloat16(a0); p.hh[1] = __float2bfloat16(a1);
            p.hh[2] = __float2bfloat16(a2); p.hh[3] = __float2bfloat16(a3);
            p.hh[4] = __float2bfloat16(a4); p.hh[5] = __float2bfloat16(a5);
            *(u3*)&aT[rr * ASTR + gl * 6] = p.uu;
        }
    }
    __syncthreads();

    // A fragments: A[m=r][k=quad*8+j]
    short8 af[3];
    #pragma unroll
    for (int ksi = 0; ksi < 3; ksi++)
        af[ksi] = *(const short8*)&aT[(wr0 + r) * ASTR + ksi * 32 + quad * 8];

    // ---- pass 1 ----
    f32x4v c1[6];
    #pragma unroll
    for (int nt = 0; nt < 6; nt++) {
        f32x4v c = {0.f, 0.f, 0.f, 0.f};
        #pragma unroll
        for (int ksi = 0; ksi < 3; ksi++) {
            short8 bfr = *(const short8*)&wS[(nt * 16 + r) * WSTR + ksi * 32 + quad * 8];
            c = __builtin_amdgcn_mfma_f32_16x16x32_bf16(af[ksi], bfr, c, 0, 0, 0);
        }
        c1[nt] = c;
    }
    __syncthreads();                                 // everyone done reading W1

    // y1 = relu(c + b1) -> bf16 into own band of aT; restage W2
    #pragma unroll
    for (int nt = 0; nt < 6; nt++) {
        float bv = B1[nt * 16 + r];
        #pragma unroll
        for (int i = 0; i < 4; i++) {
            float y = fmaxf(c1[nt][i] + bv, 0.f);
            __hip_bfloat16 hb = __float2bfloat16(y);
            aT[(wr0 + quad * 4 + i) * ASTR + nt * 16 + r] = *(short*)&hb;
        }
    }
    {
        const unsigned* wsrc = (const unsigned*)w2t;
        unsigned* wdst = (unsigned*)wS;
        for (int idx = tid; idx < 96 * WSTR / 2; idx += 256) wdst[idx] = wsrc[idx];
    }
    __syncthreads();

    // ---- pass 2 ----
    short8 af2[3];
    #pragma unroll
    for (int ksi = 0; ksi < 3; ksi++)
        af2[ksi] = *(const short8*)&aT[(wr0 + r) * ASTR + ksi * 32 + quad * 8];

    #pragma unroll
    for (int nt = 0; nt < 6; nt++) {
        f32x4v c = {0.f, 0.f, 0.f, 0.f};
        #pragma unroll
        for (int ksi = 0; ksi < 3; ksi++) {
            short8 bfr = *(const short8*)&wS[(nt * 16 + r) * WSTR + ksi * 32 + quad * 8];
            c = __builtin_amdgcn_mfma_f32_16x16x32_bf16(af2[ksi], bfr, c, 0, 0, 0);
        }
        float bv = B2[nt * 16 + r];
        int col = nt * 16 + r;
        #pragma unroll
        for (int i = 0; i < 4; i++) {
            int gr = row0 + wr0 + quad * 4 + i;
            if (gr < n) {
                float v = c[i] + bv;
                out[(size_t)gr * 384 + ocol + col] = v;
                hout[(size_t)gr * D + col] = __float2bfloat16(v);
            }
        }
    }
}

extern "C" void kernel_launch(void* const* d_in, const int* in_sizes, int n_in,
                              void* d_out, int out_size, void* d_ws, size_t ws_size,
                              hipStream_t stream) {
    const float* x = (const float*)d_in[0];
    const int* ei = (const int*)d_in[1];
    const int n = in_sizes[0] / D;           // 50000
    const int E = in_sizes[1] / 2;           // 800000
    const int* src = ei;
    const int* dst = ei + E;
    float* out = (float*)d_out;

    // workspace layout (byte offsets, all 16B-aligned)
    char* ws = (char*)d_ws;
    __hip_bfloat16* h_a  = (__hip_bfloat16*)ws;                  // n*96 halves = 9.6 MB
    __hip_bfloat16* h_b  = (__hip_bfloat16*)(ws + 9600000);      // n*96 halves = 9.6 MB
    __hip_bfloat16* wTg  = (__hip_bfloat16*)(ws + 19200000);     // 6*96*104 halves ~ 120 KB
    int*   rowcnt   = (int*)(ws + 19400000);                     // n ints = 200 KB
    int*   rowstart = (int*)(ws + 19600000);                     // n+1 ints
    unsigned short* rank = (unsigned short*)(ws + 19800016);     // E ushorts = 1.6 MB
    unsigned short* ecsr = (unsigned short*)(ws + 21400064);     // E ushorts = 1.6 MB
    int*   bsum     = (int*)(ws + 23000064);                     // <=256 ints
    int*   boff     = (int*)(ws + 23001088);                     // <=256 ints

    // out[:,0:96] = x ; h_a = bf16(x)
    k_copyx<<<(n * 24 + 255) / 256, 256, 0, stream>>>(x, out, h_a, n);

    // weights -> bf16 transposed
    k_prep<<<(6 * 9216 + 255) / 256, 256, 0, stream>>>(
        (const float*)d_in[2], (const float*)d_in[4],
        (const float*)d_in[6], (const float*)d_in[8],
        (const float*)d_in[10], (const float*)d_in[12], wTg);

    // direct 1-level CSR build (once; shared by all 3 layers)
    hipMemsetAsync(rowcnt, 0, (size_t)n * sizeof(int), stream);
    k_count<<<2048, 256, 0, stream>>>(dst, rowcnt, rank, E);
    const int NBS = (n + 255) / 256;         // 196
    k_scan_up<<<NBS, 256, 0, stream>>>(rowcnt, rowstart, bsum, n);
    k_scan_mid<<<1, 256, 0, stream>>>(bsum, boff, NBS);
    k_scan_down<<<NBS, 256, 0, stream>>>(rowstart, boff, n, E);
    const int psz = (n + 7) / 8;             // 6250
    k_scatter<<<2048, 256, 0, stream>>>(src, dst, rank, rowstart, ecsr, E, psz);

    const int mlp_grid = (n + 63) / 64;

    __hip_bfloat16* hin = h_a;
    __hip_bfloat16* hout = h_b;
    for (int l = 0; l < 3; l++) {
        const float* B1 = (const float*)d_in[3 + 4 * l];
        const float* B2 = (const float*)d_in[5 + 4 * l];
        const __hip_bfloat16* w1t = wTg + (size_t)(2 * l) * (96 * WSTR);
        const __hip_bfloat16* w2t = wTg + (size_t)(2 * l + 1) * (96 * WSTR);
        k_fused<<<mlp_grid, 256, 0, stream>>>(hin, rowstart, ecsr,
                                              w1t, B1, w2t, B2,
                                              hout, out, n, (l + 1) * D);
        __hip_bfloat16* tmp = hin; hin = hout; hout = tmp;
    }
}

// Round 6
// 277.530 us; speedup vs baseline: 1.5704x; 1.0056x over previous
//
#include <hip/hip_runtime.h>
#include <hip/hip_bf16.h>

#define D 96
#define ASTR 96        // aT stride (halves): 192B rows, 16B-aligned for b128
#define WSTR 104       // weight stride (halves): 208B, 16B-aligned, benign banking

typedef __attribute__((ext_vector_type(8))) short short8;   // 8 bf16 = 4 VGPRs
typedef __attribute__((ext_vector_type(4))) float f32x4v;   // MFMA accumulator

struct u3 { unsigned x, y, z; };                            // 12B row chunk (dwordx3)

__device__ inline float blo(unsigned u) { return __uint_as_float(u << 16); }
__device__ inline float bhi(unsigned u) { return __uint_as_float(u & 0xffff0000u); }

// ---------------- front kernel: copyx + weight prep + zero(rowcnt,donecnt) ----------------
__global__ __launch_bounds__(256) void k_front(const float* __restrict__ x,
                                               float* __restrict__ out,
                                               __hip_bfloat16* __restrict__ h16,
                                               const float* __restrict__ w10,
                                               const float* __restrict__ w20,
                                               const float* __restrict__ w11,
                                               const float* __restrict__ w21,
                                               const float* __restrict__ w12,
                                               const float* __restrict__ w22,
                                               __hip_bfloat16* __restrict__ wTg,
                                               uint4* __restrict__ zero4, int n) {
    int idx = blockIdx.x * 256 + threadIdx.x;
    int w0 = n * 24;                       // copyx work: n*24 float4s
    if (idx < w0) {
        int r = idx / 24, c = idx - r * 24;
        float4 v = ((const float4*)x)[idx];
        ((float4*)out)[r * 96 + c] = v;
        union { __hip_bfloat16 hh[4]; uint2 u; } p;
        p.hh[0] = __float2bfloat16(v.x); p.hh[1] = __float2bfloat16(v.y);
        p.hh[2] = __float2bfloat16(v.z); p.hh[3] = __float2bfloat16(v.w);
        ((uint2*)h16)[idx] = p.u;
        return;
    }
    idx -= w0;
    if (idx < 6 * 9216) {                  // weight prep: fp32 [k][n] -> bf16 T [n][k]
        int m = idx / 9216, i = idx - m * 9216;
        int k = i / 96, nn = i - k * 96;
        const float* W;
        switch (m) {
            case 0: W = w10; break; case 1: W = w20; break;
            case 2: W = w11; break; case 3: W = w21; break;
            case 4: W = w12; break; default: W = w22; break;
        }
        wTg[(size_t)m * (96 * WSTR) + nn * WSTR + k] = __float2bfloat16(W[k * 96 + nn]);
        return;
    }
    idx -= 6 * 9216;
    int zcnt = (n + 4 + 3) >> 2;           // rowcnt[n] + donecnt, in uint4s
    if (idx < zcnt) zero4[idx] = make_uint4(0, 0, 0, 0);
}

// ---------------- per-node in-degree histogram; atomic return value = edge rank ----------------
__global__ __launch_bounds__(256) void k_count(const int* __restrict__ dst,
                                               int* __restrict__ cnt,
                                               unsigned short* __restrict__ rank, int E) {
    int stride = gridDim.x * 256;
    for (int e = blockIdx.x * 256 + threadIdx.x; e < E; e += stride)
        rank[e] = (unsigned short)atomicAdd(&cnt[dst[e]], 1);
}

// ---------------- scan: per-block exclusive partials + last-block scans block sums ----------------
// bsum handoff is cross-XCD: use device-scope atomics for write and read (L2s not coherent).
__global__ __launch_bounds__(256) void k_scan(const int* __restrict__ cnt,
                                              int* __restrict__ raw,
                                              int* __restrict__ bsum,
                                              int* __restrict__ boff,
                                              unsigned* __restrict__ donecnt,
                                              int nb, int n) {
    __shared__ int s[256];
    __shared__ int lastflag;
    int t = threadIdx.x, b = blockIdx.x;
    int i = b * 256 + t;
    int v = (i < n) ? cnt[i] : 0;
    s[t] = v;
    __syncthreads();
    for (int off = 1; off < 256; off <<= 1) {
        int u = (t >= off) ? s[t - off] : 0;
        __syncthreads();
        s[t] += u;
        __syncthreads();
    }
    if (i < n) raw[i] = s[t] - v;          // exclusive within block
    if (t == 255) {
        atomicExch(&bsum[b], s[255]);      // device-scope publish of block total
        __threadfence();
        unsigned d = atomicAdd(donecnt, 1);
        lastflag = (d == (unsigned)(nb - 1));
    }
    __syncthreads();
    if (lastflag) {                        // last-arriving block scans the block sums
        int vv = (t < nb) ? atomicAdd(&bsum[t], 0) : 0;   // device-scope read
        s[t] = vv;
        __syncthreads();
        for (int off = 1; off < 256; off <<= 1) {
            int u = (t >= off) ? s[t - off] : 0;
            __syncthreads();
            s[t] += u;
            __syncthreads();
        }
        if (t < nb) boff[t] = s[t] - vv;   // exclusive block offsets
    }
}

// ---------------- atomic-free XCD-partitioned scatter ----------------
// partition p = blockIdx&7 owns dst in [p*psz,(p+1)*psz): its ~200KB ecsr window
// write-combines in one XCD's L2. pos = raw[d] + boff[d>>8] + rank[e].
__global__ __launch_bounds__(256) void k_scatter(const int* __restrict__ src,
                                                 const int* __restrict__ dst,
                                                 const unsigned short* __restrict__ rank,
                                                 const int* __restrict__ raw,
                                                 const int* __restrict__ boff,
                                                 unsigned short* __restrict__ ecsr,
                                                 int E, int psz) {
    int part = blockIdx.x & 7;
    int lo = part * psz;
    int hi = lo + psz;
    int bi = blockIdx.x >> 3;
    int nb = gridDim.x >> 3;
    int stride = nb * 256;
    for (int e = bi * 256 + threadIdx.x; e < E; e += stride) {
        int d = dst[e];
        if (d >= lo && d < hi)
            ecsr[raw[d] + boff[d >> 8] + (int)rank[e]] = (unsigned short)src[e];
    }
}

// ---------------- fused layer: aggregate into LDS, then MFMA MLP ----------------
// 64 rows/block, 256 threads, 5 blocks/CU (LDS 32,256B, VGPR capped via launch_bounds).
__global__ __launch_bounds__(256, 5) void k_fused(const __hip_bfloat16* __restrict__ hin,
                                                  const int* __restrict__ raw,
                                                  const int* __restrict__ boff,
                                                  const unsigned short* __restrict__ ecsr,
                                                  const __hip_bfloat16* __restrict__ w1t,
                                                  const float* __restrict__ B1,
                                                  const __hip_bfloat16* __restrict__ w2t,
                                                  const float* __restrict__ B2,
                                                  __hip_bfloat16* __restrict__ hout,
                                                  float* __restrict__ out,
                                                  int n, int E, int ocol) {
    __shared__ __align__(16) short aT[64 * ASTR];   // aggregated rows / y1, bf16
    __shared__ __align__(16) short wS[96 * WSTR];   // current weight, bf16 transposed

    const int tid = threadIdx.x;
    const int row0 = blockIdx.x * 64;
    const int lane = tid & 63;
    const int wv = __builtin_amdgcn_readfirstlane(tid >> 6);
    const int wr0 = wv * 16;                         // wave's row band
    const int quad = lane >> 4;
    const int r = lane & 15;

    // stage W1 (issues first; lands under the gather latency)
    {
        const unsigned* wsrc = (const unsigned*)w1t;
        unsigned* wdst = (unsigned*)wS;
        for (int idx = tid; idx < 96 * WSTR / 2; idx += 256) wdst[idx] = wsrc[idx];
    }

    // ---- aggregation phase: t[i] = h[i] + sum_j h[src_j], straight into aT ----
    {
        const int ng = tid >> 4;                    // node-group 0..15
        const int gl = tid & 15;                    // lane within group
        const u3* hp = (const u3*)hin;              // 16 u3 per 192B row
        #pragma unroll
        for (int it = 0; it < 4; it++) {
            int rr = ng + it * 16;                  // local row 0..63
            int gr = row0 + rr; if (gr >= n) gr = n - 1;
            u3 u = hp[(size_t)gr * 16 + gl];        // self term (eps=0)
            float a0 = blo(u.x), a1 = bhi(u.x), a2 = blo(u.y),
                  a3 = bhi(u.y), a4 = blo(u.z), a5 = bhi(u.z);
            int e0 = raw[gr] + boff[gr >> 8];
            int e1 = (gr + 1 == n) ? E : raw[gr + 1] + boff[(gr + 1) >> 8];
            int k = e0;
            for (; k + 8 <= e1; k += 8) {           // 8 gathers in flight
                int s0 = ecsr[k],     s1 = ecsr[k + 1], s2 = ecsr[k + 2], s3 = ecsr[k + 3];
                int s4 = ecsr[k + 4], s5 = ecsr[k + 5], s6 = ecsr[k + 6], s7 = ecsr[k + 7];
                u3 v0 = hp[(size_t)s0 * 16 + gl];
                u3 v1 = hp[(size_t)s1 * 16 + gl];
                u3 v2 = hp[(size_t)s2 * 16 + gl];
                u3 v3 = hp[(size_t)s3 * 16 + gl];
                u3 v4 = hp[(size_t)s4 * 16 + gl];
                u3 v5 = hp[(size_t)s5 * 16 + gl];
                u3 v6 = hp[(size_t)s6 * 16 + gl];
                u3 v7 = hp[(size_t)s7 * 16 + gl];
                a0 += blo(v0.x) + blo(v1.x) + blo(v2.x) + blo(v3.x)
                    + blo(v4.x) + blo(v5.x) + blo(v6.x) + blo(v7.x);
                a1 += bhi(v0.x) + bhi(v1.x) + bhi(v2.x) + bhi(v3.x)
                    + bhi(v4.x) + bhi(v5.x) + bhi(v6.x) + bhi(v7.x);
                a2 += blo(v0.y) + blo(v1.y) + blo(v2.y) + blo(v3.y)
                    + blo(v4.y) + blo(v5.y) + blo(v6.y) + blo(v7.y);
                a3 += bhi(v0.y) + bhi(v1.y) + bhi(v2.y) + bhi(v3.y)
                    + bhi(v4.y) + bhi(v5.y) + bhi(v6.y) + bhi(v7.y);
                a4 += blo(v0.z) + blo(v1.z) + blo(v2.z) + blo(v3.z)
                    + blo(v4.z) + blo(v5.z) + blo(v6.z) + blo(v7.z);
                a5 += bhi(v0.z) + bhi(v1.z) + bhi(v2.z) + bhi(v3.z)
                    + bhi(v4.z) + bhi(v5.z) + bhi(v6.z) + bhi(v7.z);
            }
            for (; k + 4 <= e1; k += 4) {
                int s0 = ecsr[k], s1 = ecsr[k + 1], s2 = ecsr[k + 2], s3 = ecsr[k + 3];
                u3 v0 = hp[(size_t)s0 * 16 + gl];
                u3 v1 = hp[(size_t)s1 * 16 + gl];
                u3 v2 = hp[(size_t)s2 * 16 + gl];
                u3 v3 = hp[(size_t)s3 * 16 + gl];
                a0 += blo(v0.x) + blo(v1.x) + blo(v2.x) + blo(v3.x);
                a1 += bhi(v0.x) + bhi(v1.x) + bhi(v2.x) + bhi(v3.x);
                a2 += blo(v0.y) + blo(v1.y) + blo(v2.y) + blo(v3.y);
                a3 += bhi(v0.y) + bhi(v1.y) + bhi(v2.y) + bhi(v3.y);
                a4 += blo(v0.z) + blo(v1.z) + blo(v2.z) + blo(v3.z);
                a5 += bhi(v0.z) + bhi(v1.z) + bhi(v2.z) + bhi(v3.z);
            }
            for (; k < e1; k++) {
                int s = ecsr[k];
                u3 v = hp[(size_t)s * 16 + gl];
                a0 += blo(v.x); a1 += bhi(v.x); a2 += blo(v.y);
                a3 += bhi(v.y); a4 += blo(v.z); a5 += bhi(v.z);
            }
            union { __hip_bfloat16 hh[6]; u3 uu; } p;
            p.hh[0] = __float2bfloat16(a0); p.hh[1] = __float2bfloat16(a1);
            p.hh[2] = __float2bfloat16(a2); p.hh[3] = __float2bfloat16(a3);
            p.hh[4] = __float2bfloat16(a4); p.hh[5] = __float2bfloat16(a5);
            *(u3*)&aT[rr * ASTR + gl * 6] = p.uu;
        }
    }
    __syncthreads();

    // A fragments: A[m=r][k=quad*8+j]
    short8 af[3];
    #pragma unroll
    for (int ksi = 0; ksi < 3; ksi++)
        af[ksi] = *(const short8*)&aT[(wr0 + r) * ASTR + ksi * 32 + quad * 8];

    // ---- pass 1 ----
    f32x4v c1[6];
    #pragma unroll
    for (int nt = 0; nt < 6; nt++) {
        f32x4v c = {0.f, 0.f, 0.f, 0.f};
        #pragma unroll
        for (int ksi = 0; ksi < 3; ksi++) {
            short8 bfr = *(const short8*)&wS[(nt * 16 + r) * WSTR + ksi * 32 + quad * 8];
            c = __builtin_amdgcn_mfma_f32_16x16x32_bf16(af[ksi], bfr, c, 0, 0, 0);
        }
        c1[nt] = c;
    }
    __syncthreads();                                 // everyone done reading W1

    // y1 = relu(c + b1) -> bf16 into own band of aT; restage W2
    #pragma unroll
    for (int nt = 0; nt < 6; nt++) {
        float bv = B1[nt * 16 + r];
        #pragma unroll
        for (int i = 0; i < 4; i++) {
            float y = fmaxf(c1[nt][i] + bv, 0.f);
            __hip_bfloat16 hb = __float2bfloat16(y);
            aT[(wr0 + quad * 4 + i) * ASTR + nt * 16 + r] = *(short*)&hb;
        }
    }
    {
        const unsigned* wsrc = (const unsigned*)w2t;
        unsigned* wdst = (unsigned*)wS;
        for (int idx = tid; idx < 96 * WSTR / 2; idx += 256) wdst[idx] = wsrc[idx];
    }
    __syncthreads();

    // ---- pass 2 ----
    short8 af2[3];
    #pragma unroll
    for (int ksi = 0; ksi < 3; ksi++)
        af2[ksi] = *(const short8*)&aT[(wr0 + r) * ASTR + ksi * 32 + quad * 8];

    #pragma unroll
    for (int nt = 0; nt < 6; nt++) {
        f32x4v c = {0.f, 0.f, 0.f, 0.f};
        #pragma unroll
        for (int ksi = 0; ksi < 3; ksi++) {
            short8 bfr = *(const short8*)&wS[(nt * 16 + r) * WSTR + ksi * 32 + quad * 8];
            c = __builtin_amdgcn_mfma_f32_16x16x32_bf16(af2[ksi], bfr, c, 0, 0, 0);
        }
        float bv = B2[nt * 16 + r];
        int col = nt * 16 + r;
        #pragma unroll
        for (int i = 0; i < 4; i++) {
            int gr = row0 + wr0 + quad * 4 + i;
            if (gr < n) {
                float v = c[i] + bv;
                out[(size_t)gr * 384 + ocol + col] = v;
                hout[(size_t)gr * D + col] = __float2bfloat16(v);
            }
        }
    }
}

extern "C" void kernel_launch(void* const* d_in, const int* in_sizes, int n_in,
                              void* d_out, int out_size, void* d_ws, size_t ws_size,
                              hipStream_t stream) {
    const float* x = (const float*)d_in[0];
    const int* ei = (const int*)d_in[1];
    const int n = in_sizes[0] / D;           // 50000
    const int E = in_sizes[1] / 2;           // 800000
    const int* src = ei;
    const int* dst = ei + E;
    float* out = (float*)d_out;

    // workspace layout (byte offsets, all 16B-aligned)
    char* ws = (char*)d_ws;
    __hip_bfloat16* h_a  = (__hip_bfloat16*)ws;                  // n*96 halves = 9.6 MB
    __hip_bfloat16* h_b  = (__hip_bfloat16*)(ws + 9600000);      // n*96 halves = 9.6 MB
    __hip_bfloat16* wTg  = (__hip_bfloat16*)(ws + 19200000);     // 6*96*104 halves ~ 120 KB
    int*      rowcnt  = (int*)(ws + 19400000);                   // n ints = 200 KB
    unsigned* donecnt = (unsigned*)(ws + 19600000);              // 16 B (zeroed with rowcnt)
    int*      raw     = (int*)(ws + 19600016);                   // n ints (block-local excl)
    int*      bsum    = (int*)(ws + 19800032);                   // <=256 ints
    int*      boff    = (int*)(ws + 19801056);                   // <=256 ints
    unsigned short* rank = (unsigned short*)(ws + 19802080);     // E ushorts = 1.6 MB
    unsigned short* ecsr = (unsigned short*)(ws + 21402080);     // E ushorts = 1.6 MB

    // front: out[:,0:96]=x, h_a=bf16(x), weights->bf16T, zero rowcnt+donecnt
    const int zcnt = (n + 4 + 3) >> 2;
    const int front_work = n * 24 + 6 * 9216 + zcnt;
    k_front<<<(front_work + 255) / 256, 256, 0, stream>>>(
        x, out, h_a,
        (const float*)d_in[2], (const float*)d_in[4],
        (const float*)d_in[6], (const float*)d_in[8],
        (const float*)d_in[10], (const float*)d_in[12],
        wTg, (uint4*)rowcnt, n);

    // CSR build: count(+rank), scan(up+mid fused), scatter (atomic-free, XCD-partitioned)
    k_count<<<2048, 256, 0, stream>>>(dst, rowcnt, rank, E);
    const int NBS = (n + 255) / 256;         // 196
    k_scan<<<NBS, 256, 0, stream>>>(rowcnt, raw, bsum, boff, donecnt, NBS, n);
    const int psz = (n + 7) / 8;             // 6250
    k_scatter<<<2048, 256, 0, stream>>>(src, dst, rank, raw, boff, ecsr, E, psz);

    const int mlp_grid = (n + 63) / 64;

    __hip_bfloat16* hin = h_a;
    __hip_bfloat16* hout = h_b;
    for (int l = 0; l < 3; l++) {
        const float* B1 = (const float*)d_in[3 + 4 * l];
        const float* B2 = (const float*)d_in[5 + 4 * l];
        const __hip_bfloat16* w1t = wTg + (size_t)(2 * l) * (96 * WSTR);
        const __hip_bfloat16* w2t = wTg + (size_t)(2 * l + 1) * (96 * WSTR);
        k_fused<<<mlp_grid, 256, 0, stream>>>(hin, raw, boff, ecsr,
                                              w1t, B1, w2t, B2,
                                              hout, out, n, E, (l + 1) * D);
        __hip_bfloat16* tmp = hin; hin = hout; hout = tmp;
    }
}